// Round 9
// baseline (449.409 us; speedup 1.0000x reference)
//
#include <hip/hip_runtime.h>
#include <hip/hip_bf16.h>
#include <math.h>

#define N_EMBD 1024
#define N_HEADC 16
#define HEAD_D 64

typedef __attribute__((ext_vector_type(8))) short short8;
typedef __attribute__((ext_vector_type(4))) float floatx4;

__device__ __forceinline__ ushort f2b(float f) {
    __hip_bfloat16 h = __float2bfloat16(f);
    return *reinterpret_cast<ushort*>(&h);
}

__device__ __forceinline__ void async_cp16(const void* gsrc, void* ldst) {
    __builtin_amdgcn_global_load_lds(
        (const __attribute__((address_space(1))) void*)gsrc,
        (__attribute__((address_space(3))) void*)ldst, 16, 0, 0);
}

// Bijective XCD-chunk swizzle (m204 form).
__device__ __forceinline__ int xcd_swizzle(int bid, int nwg) {
    const int q = nwg >> 3, r = nwg & 7;
    const int xcd = bid & 7, loc = bid >> 3;
    return (xcd < r ? xcd * (q + 1) : r * (q + 1) + (xcd - r) * q) + loc;
}

// LDS column swizzle key: spreads 64B-stride rows across banks; period 8 rows
// gives distinct (bank-base, 16B-slot) pairs -> 2-way (free) on ds_read_b128.
__device__ __forceinline__ int swzkey(int row) { return ((row >> 1) & 3) << 3; }

// ---------------------------------------------------------------------------
// LayerNorm: fp32 in, bf16 out. One block (256 thr) per row of C=1024.
// ---------------------------------------------------------------------------
__global__ __launch_bounds__(256) void ln_kernel(const float* __restrict__ x,
                                                 const float* __restrict__ w,
                                                 const float* __restrict__ b,
                                                 ushort* __restrict__ out) {
    const int row = blockIdx.x;
    const int t = threadIdx.x;
    const float4 v = reinterpret_cast<const float4*>(x + (size_t)row * N_EMBD)[t];
    float s  = v.x + v.y + v.z + v.w;
    float ss = v.x * v.x + v.y * v.y + v.z * v.z + v.w * v.w;
    for (int o = 32; o > 0; o >>= 1) {
        s  += __shfl_down(s, o);
        ss += __shfl_down(ss, o);
    }
    __shared__ float as_[4], ass_[4];
    const int wid = t >> 6, lane = t & 63;
    if (lane == 0) { as_[wid] = s; ass_[wid] = ss; }
    __syncthreads();
    const float ts  = as_[0] + as_[1] + as_[2] + as_[3];
    const float tss = ass_[0] + ass_[1] + ass_[2] + ass_[3];
    const float mu  = ts * (1.f / N_EMBD);
    const float var = tss * (1.f / N_EMBD) - mu * mu;
    const float inv = rsqrtf(var + 1e-5f);
    const float4 wv = reinterpret_cast<const float4*>(w)[t];
    const float4 bv = reinterpret_cast<const float4*>(b)[t];
    ushort4 o;
    o.x = f2b((v.x - mu) * inv * wv.x + bv.x);
    o.y = f2b((v.y - mu) * inv * wv.y + bv.y);
    o.z = f2b((v.z - mu) * inv * wv.z + bv.z);
    o.w = f2b((v.w - mu) * inv * wv.w + bv.w);
    reinterpret_cast<ushort4*>(out + (size_t)row * N_EMBD)[t] = o;
}

// ---------------------------------------------------------------------------
// Transpose + convert: W[K,N] fp32 -> Wt[N,K] bf16. 32x32 tiles, 256 thr.
// ---------------------------------------------------------------------------
__global__ void convtrans_kernel(const float* __restrict__ W,
                                 ushort* __restrict__ Wt, int K, int N) {
    __shared__ float tile[32][33];
    const int tid = threadIdx.x;
    const int r = tid >> 3;
    const int c4 = (tid & 7) * 4;
    const int bx = blockIdx.x, by = blockIdx.y;

    float4 v = *(const float4*)&W[((size_t)(by * 32 + r)) * N + bx * 32 + c4];
    tile[r][c4 + 0] = v.x; tile[r][c4 + 1] = v.y;
    tile[r][c4 + 2] = v.z; tile[r][c4 + 3] = v.w;
    __syncthreads();

    ushort4 u;
    u.x = f2b(tile[c4 + 0][r]); u.y = f2b(tile[c4 + 1][r]);
    u.z = f2b(tile[c4 + 2][r]); u.w = f2b(tile[c4 + 3][r]);
    *(ushort4*)&Wt[((size_t)(bx * 32 + r)) * K + by * 32 + c4] = u;
}

// ---------------------------------------------------------------------------
// 128^2 bf16 MFMA GEMM (counted vmcnt dbuf) — kept for proj (N=1024, K=1024).
// ---------------------------------------------------------------------------
__device__ __forceinline__ void gemm_stage(
        const ushort* __restrict__ A, const ushort* __restrict__ Bt,
        ushort* As, ushort* Bs,
        int m0, int n0, int K, int k0, int w, int lane) {
#pragma unroll
    for (int l = 0; l < 2; l++) {
        const int cbase = w * 128 + l * 64;
        const int c = cbase + lane;
        const int row = c >> 2, kc8 = (c & 3) * 8;
        async_cp16(A  + (size_t)(m0 + row) * K + k0 + kc8, &As[cbase * 8]);
        async_cp16(Bt + (size_t)(n0 + row) * K + k0 + kc8, &Bs[cbase * 8]);
    }
}

__device__ __forceinline__ void gemm_compute(
        const ushort* As, const ushort* Bs, floatx4 (*acc)[4],
        int wm, int wn, int quad, int l16) {
    short8 a[4], bf[4];
#pragma unroll
    for (int i = 0; i < 4; i++)
        a[i] = *(const short8*)&As[(wm * 64 + i * 16 + l16) * 32 + quad * 8];
#pragma unroll
    for (int j = 0; j < 4; j++)
        bf[j] = *(const short8*)&Bs[(wn * 64 + j * 16 + l16) * 32 + quad * 8];
#pragma unroll
    for (int i = 0; i < 4; i++)
#pragma unroll
        for (int j = 0; j < 4; j++)
            acc[i][j] = __builtin_amdgcn_mfma_f32_16x16x32_bf16(
                a[i], bf[j], acc[i][j], 0, 0, 0);
}

__global__ __launch_bounds__(256) void gemm_bf16_kernel(
        const ushort* __restrict__ A,
        const ushort* __restrict__ Bt,
        const float* __restrict__ bias,
        const float* __restrict__ residual,
        float* __restrict__ out32,
        ushort* __restrict__ out16,
        int M, int N, int K, int do_gelu) {
    __shared__ ushort As[2][128 * 32];
    __shared__ ushort Bs[2][128 * 32];

    const int tid  = threadIdx.x;
    const int w    = tid >> 6;
    const int lane = tid & 63;
    const int quad = lane >> 4;
    const int l16  = lane & 15;
    const int wm   = w >> 1;
    const int wn   = w & 1;

    int bid = blockIdx.y * gridDim.x + blockIdx.x;
    bid = xcd_swizzle(bid, gridDim.x * gridDim.y);
    const int bx = bid % gridDim.x;
    const int by = bid / gridDim.x;
    const int m0 = by * 128;
    const int n0 = bx * 128;

    const int kchunk = K / gridDim.z;
    const int kbeg   = blockIdx.z * kchunk;
    if (gridDim.z > 1)
        out32 += (size_t)blockIdx.z * M * N;

    floatx4 acc[4][4];
#pragma unroll
    for (int i = 0; i < 4; i++)
#pragma unroll
        for (int j = 0; j < 4; j++) acc[i][j] = (floatx4){0.f, 0.f, 0.f, 0.f};

    const int nt = kchunk >> 5;

    gemm_stage(A, Bt, As[0], Bs[0], m0, n0, K, kbeg, w, lane);
    gemm_stage(A, Bt, As[1], Bs[1], m0, n0, K, kbeg + 32, w, lane);

    for (int t = 0; t < nt; t++) {
        if (t + 1 < nt) {
            asm volatile("s_waitcnt vmcnt(4)" ::: "memory");
        } else {
            asm volatile("s_waitcnt vmcnt(0)" ::: "memory");
        }
        __builtin_amdgcn_sched_barrier(0);
        __builtin_amdgcn_s_barrier();

        gemm_compute(As[t & 1], Bs[t & 1], acc, wm, wn, quad, l16);

        __builtin_amdgcn_s_barrier();
        if (t + 2 < nt)
            gemm_stage(A, Bt, As[t & 1], Bs[t & 1],
                       m0, n0, K, kbeg + ((t + 2) << 5), w, lane);
    }

#pragma unroll
    for (int i = 0; i < 4; i++) {
#pragma unroll
        for (int j = 0; j < 4; j++) {
            const int nn = n0 + wn * 64 + j * 16 + l16;
            const float bv = bias ? bias[nn] : 0.f;
#pragma unroll
            for (int r = 0; r < 4; r++) {
                const int mm = m0 + wm * 64 + i * 16 + quad * 4 + r;
                float v = acc[i][j][r] + bv;
                if (do_gelu) v = 0.5f * v * (1.f + erff(v * 0.70710678118654752f));
                if (residual) v += residual[(size_t)mm * N + nn];
                if (out32) out32[(size_t)mm * N + nn] = v;
                if (out16) out16[(size_t)mm * N + nn] = f2b(v);
            }
        }
    }
}

// ---------------------------------------------------------------------------
// 256^2 bf16 MFMA GEMM: 512 thr, 8 waves (2x4), per-wave 128x64 (acc[8][4]).
// 2x LDS intensity vs 128^2 (the 128^2 kernel is LDS-BW-bound). Source-pre-
// swizzled LDS columns (swzkey) -> conflict-free ds_read_b128. Counted vmcnt.
// ---------------------------------------------------------------------------
__device__ __forceinline__ void gemm256_stage(
        const ushort* __restrict__ A, const ushort* __restrict__ Bt,
        ushort* As, ushort* Bs,
        int m0, int n0, int K, int k0, int w, int lane) {
#pragma unroll
    for (int l = 0; l < 2; l++) {
        const int cbase = l * 512 + w * 64;
        const int c = cbase + lane;
        const int row = c >> 2;
        const int gcol = ((c & 3) * 8) ^ swzkey(row);
        async_cp16(A  + (size_t)(m0 + row) * K + k0 + gcol, &As[cbase * 8]);
        async_cp16(Bt + (size_t)(n0 + row) * K + k0 + gcol, &Bs[cbase * 8]);
    }
}
// 4 global_load_lds per wave per stage -> vmcnt quantum 4.

__device__ __forceinline__ void gemm256_compute(
        const ushort* As, const ushort* Bs, floatx4 (*acc)[4],
        int wr, int wc, int quad, int l16) {
    short8 a[8], b[4];
#pragma unroll
    for (int i = 0; i < 8; i++) {
        const int row = wr * 128 + i * 16 + l16;
        a[i] = *(const short8*)&As[row * 32 + ((quad * 8) ^ swzkey(row))];
    }
#pragma unroll
    for (int j = 0; j < 4; j++) {
        const int row = wc * 64 + j * 16 + l16;
        b[j] = *(const short8*)&Bs[row * 32 + ((quad * 8) ^ swzkey(row))];
    }
#pragma unroll
    for (int i = 0; i < 8; i++)
#pragma unroll
        for (int j = 0; j < 4; j++)
            acc[i][j] = __builtin_amdgcn_mfma_f32_16x16x32_bf16(
                a[i], b[j], acc[i][j], 0, 0, 0);
}

__global__ __launch_bounds__(512, 2) void gemm256_bf16_kernel(
        const ushort* __restrict__ A,
        const ushort* __restrict__ Bt,
        const float* __restrict__ bias,
        const float* __restrict__ residual,
        float* __restrict__ out32,
        ushort* __restrict__ out16,
        int M, int N, int K, int do_gelu) {
    __shared__ ushort As[2][256 * 32];
    __shared__ ushort Bs[2][256 * 32];

    const int tid  = threadIdx.x;
    const int w    = tid >> 6;
    const int lane = tid & 63;
    const int quad = lane >> 4;
    const int l16  = lane & 15;
    const int wr   = w >> 2;      // 0..1
    const int wc   = w & 3;       // 0..3

    int bid = blockIdx.y * gridDim.x + blockIdx.x;
    bid = xcd_swizzle(bid, gridDim.x * gridDim.y);
    const int bx = bid % gridDim.x;
    const int by = bid / gridDim.x;
    const int m0 = by * 256;
    const int n0 = bx * 256;

    const int kchunk = K / gridDim.z;
    const int kbeg   = blockIdx.z * kchunk;
    if (gridDim.z > 1)
        out32 += (size_t)blockIdx.z * M * N;

    floatx4 acc[8][4];
#pragma unroll
    for (int i = 0; i < 8; i++)
#pragma unroll
        for (int j = 0; j < 4; j++) acc[i][j] = (floatx4){0.f, 0.f, 0.f, 0.f};

    const int nt = kchunk >> 5;   // >= 32 at all call sites

    gemm256_stage(A, Bt, As[0], Bs[0], m0, n0, K, kbeg, w, lane);
    gemm256_stage(A, Bt, As[1], Bs[1], m0, n0, K, kbeg + 32, w, lane);

    for (int t = 0; t < nt; t++) {
        if (t + 1 < nt) {
            asm volatile("s_waitcnt vmcnt(4)" ::: "memory");
        } else {
            asm volatile("s_waitcnt vmcnt(0)" ::: "memory");
        }
        __builtin_amdgcn_sched_barrier(0);
        __builtin_amdgcn_s_barrier();

        gemm256_compute(As[t & 1], Bs[t & 1], acc, wr, wc, quad, l16);

        __builtin_amdgcn_s_barrier();
        if (t + 2 < nt)
            gemm256_stage(A, Bt, As[t & 1], Bs[t & 1],
                          m0, n0, K, kbeg + ((t + 2) << 5), w, lane);
    }

#pragma unroll
    for (int i = 0; i < 8; i++) {
#pragma unroll
        for (int j = 0; j < 4; j++) {
            const int nn = n0 + wc * 64 + j * 16 + l16;
            const float bv = bias ? bias[nn] : 0.f;
#pragma unroll
            for (int r = 0; r < 4; r++) {
                const int mm = m0 + wr * 128 + i * 16 + quad * 4 + r;
                float v = acc[i][j][r] + bv;
                if (do_gelu) v = 0.5f * v * (1.f + erff(v * 0.70710678118654752f));
                if (residual) v += residual[(size_t)mm * N + nn];
                if (out32) out32[(size_t)mm * N + nn] = v;
                if (out16) out16[(size_t)mm * N + nn] = f2b(v);
            }
        }
    }
}

// ---------------------------------------------------------------------------
// Split-K combine: out(x1) += p0 + p1 + bias. One float4 per thread.
// ---------------------------------------------------------------------------
__global__ __launch_bounds__(256) void combine_kernel(
        const float* __restrict__ p0, const float* __restrict__ p1,
        const float* __restrict__ bias, float* __restrict__ out) {
    const int i = blockIdx.x * 256 + threadIdx.x;
    const float4 a = ((const float4*)p0)[i];
    const float4 c = ((const float4*)p1)[i];
    const float4 bb = ((const float4*)bias)[i & 255];
    float4 o = ((float4*)out)[i];
    o.x += a.x + c.x + bb.x;
    o.y += a.y + c.y + bb.y;
    o.z += a.z + c.z + bb.z;
    o.w += a.w + c.w + bb.w;
    ((float4*)out)[i] = o;
}

// ---------------------------------------------------------------------------
// Flash ALiBi attention, SWAPPED QK^T (unchanged from R6/R7).
// ---------------------------------------------------------------------------
#define AT_PAD 72
#define LOG2E 1.4426950408889634f

__device__ __forceinline__ void attn_tile_step(
        short8 aq0, short8 aq1,
        ushort (*__restrict__ Ks)[AT_PAD],
        ushort (*__restrict__ Vt)[AT_PAD],
        ushort (*__restrict__ Ps)[AT_PAD],
        float& m_row, float& l_row, floatx4* acc,
        int qrow, int kt, bool domask,
        float qs2, float alibi_q, float skb16, const float* skq4,
        int w, int quad, int l16, int lane) {
    floatx4 sfrag[4];
#pragma unroll
    for (int kb = 0; kb < 4; kb++) {
        const int krow = kb * 16 + l16;
        short8 ak0 = *(const short8*)&Ks[krow][quad * 8];
        short8 ak1 = *(const short8*)&Ks[krow][32 + quad * 8];
        floatx4 s = (floatx4){0.f, 0.f, 0.f, 0.f};
        s = __builtin_amdgcn_mfma_f32_16x16x32_bf16(ak0, aq0, s, 0, 0, 0);
        s = __builtin_amdgcn_mfma_f32_16x16x32_bf16(ak1, aq1, s, 0, 0, 0);
        sfrag[kb] = s;
    }

    const float rowc = alibi_q - skb16 * (float)(kt * 4);
    float sv[4][4];
    float rm = -INFINITY;
#pragma unroll
    for (int kb = 0; kb < 4; kb++) {
        const float rck = rowc - skb16 * (float)kb;
#pragma unroll
        for (int r = 0; r < 4; r++) {
            float s = fmaf(sfrag[kb][r], qs2, rck - skq4[r]);
            if (domask) {
                const int k = kt * 64 + kb * 16 + quad * 4 + r;
                s = (k <= qrow) ? s : -INFINITY;
            }
            sv[kb][r] = s;
            rm = fmaxf(rm, s);
        }
    }
    rm = fmaxf(rm, __shfl_xor(rm, 16));
    rm = fmaxf(rm, __shfl_xor(rm, 32));

    if (__any(rm > m_row)) {
        const float mn = fmaxf(rm, m_row);
        const float corr = exp2f(m_row - mn);
        m_row = mn;
        l_row *= corr;
        float cr[4];
#pragma unroll
        for (int r = 0; r < 4; r++)
            cr[r] = __shfl(corr, (lane & 48) + quad * 4 + r);
#pragma unroll
        for (int db = 0; db < 4; db++)
#pragma unroll
            for (int r = 0; r < 4; r++) acc[db][r] *= cr[r];
    }

    float rs = 0.f;
#pragma unroll
    for (int kb = 0; kb < 4; kb++) {
        const float p0 = exp2f(sv[kb][0] - m_row);
        const float p1 = exp2f(sv[kb][1] - m_row);
        const float p2 = exp2f(sv[kb][2] - m_row);
        const float p3 = exp2f(sv[kb][3] - m_row);
        rs += (p0 + p1) + (p2 + p3);
        ushort4 pw;
        pw.x = f2b(p0); pw.y = f2b(p1); pw.z = f2b(p2); pw.w = f2b(p3);
        *(ushort4*)&Ps[w * 16 + l16][kb * 16 + quad * 4] = pw;
    }
    rs += __shfl_xor(rs, 16);
    rs += __shfl_xor(rs, 32);
    l_row += rs;

    short8 ap0 = *(const short8*)&Ps[w * 16 + l16][quad * 8];
    short8 ap1 = *(const short8*)&Ps[w * 16 + l16][32 + quad * 8];
#pragma unroll
    for (int db = 0; db < 4; db++) {
        const int dv = db * 16 + l16;
        const int svw = ((db * 4 + (l16 >> 2)) & 7) << 3;
        short8 bv0 = *(const short8*)&Vt[dv][(quad * 8) ^ svw];
        short8 bv1 = *(const short8*)&Vt[dv][(32 + quad * 8) ^ svw];
        acc[db] = __builtin_amdgcn_mfma_f32_16x16x32_bf16(ap0, bv0, acc[db], 0, 0, 0);
        acc[db] = __builtin_amdgcn_mfma_f32_16x16x32_bf16(ap1, bv1, acc[db], 0, 0, 0);
    }
}

__global__ __launch_bounds__(256) void attn_mfma_kernel(
        const ushort* __restrict__ qkv, ushort* __restrict__ y,
        float* __restrict__ opart, float* __restrict__ mpart,
        float* __restrict__ lpart, int B, int T) {
    const int C3 = 3 * N_EMBD;

    const int lin = xcd_swizzle(blockIdx.x, gridDim.x);
    const int bh = lin / 48;
    const int s  = lin % 48;
    int qt, cc, ktb_i, kte;
    bool split;
    if (s < 32) {
        split = true;
        qt = 31 - (s >> 1);
        cc = s & 1;
        const int hc = (qt + 2) >> 1;
        ktb_i = cc ? hc : 0;
        kte   = cc ? qt : hc - 1;
    } else {
        split = false;
        qt = 47 - s;
        cc = 0;
        ktb_i = 0;
        kte = qt;
    }
    const int b = bh >> 4, h = bh & 15;

    const int tid  = threadIdx.x;
    const int lane = tid & 63;
    const int w    = tid >> 6;
    const int quad = lane >> 4;
    const int l16  = lane & 15;

    __shared__ ushort QPs[64][AT_PAD];
    __shared__ ushort Ks[64][AT_PAD];
    __shared__ ushort Vt[64][AT_PAD];

    const float slope  = exp2f(-0.5f * (float)(h + 1));
    const float slope2 = slope * LOG2E;
    const float qs2    = 0.125f * LOG2E;

    const int q0 = qt * 64;
    const int qrow = q0 + w * 16 + l16;
    const float alibi_q = slope2 * (float)qrow;
    const float skb16   = slope2 * 16.f;
    float skq4[4];
#pragma unroll
    for (int r = 0; r < 4; r++) skq4[r] = slope2 * (float)(quad * 4 + r);

    const size_t hb = (size_t)b * T * C3 + (size_t)h * HEAD_D;

    int srow[4], sd0[4], svr[4];
#pragma unroll
    for (int i = 0; i < 4; i++) {
        const int idx = tid + i * 256;
        srow[i] = idx >> 4;
        sd0[i]  = (idx & 15) * 4;
        svr[i]  = srow[i] ^ ((idx & 7) << 3);
    }

#pragma unroll
    for (int i = 0; i < 4; i++) {
        *(ushort4*)&QPs[srow[i]][sd0[i]] =
            *(const ushort4*)&qkv[hb + (size_t)(q0 + srow[i]) * C3 + sd0[i]];
    }
    __syncthreads();

    const int mrow = w * 16 + l16;
    short8 aq0 = *(const short8*)&QPs[mrow][quad * 8];
    short8 aq1 = *(const short8*)&QPs[mrow][32 + quad * 8];

    float m_row = -INFINITY, l_row = 0.f;
    floatx4 acc[4];
#pragma unroll
    for (int r = 0; r < 4; r++) acc[r] = (floatx4){0.f, 0.f, 0.f, 0.f};

#pragma unroll
    for (int i = 0; i < 4; i++) {
        const size_t src = hb + (size_t)(ktb_i * 64 + srow[i]) * C3 + sd0[i];
        *(ushort4*)&Ks[srow[i]][sd0[i]] = *(const ushort4*)&qkv[src + N_EMBD];
        ushort4 vv = *(const ushort4*)&qkv[src + 2 * N_EMBD];
        Vt[sd0[i] + 0][svr[i]] = vv.x;
        Vt[sd0[i] + 1][svr[i]] = vv.y;
        Vt[sd0[i] + 2][svr[i]] = vv.z;
        Vt[sd0[i] + 3][svr[i]] = vv.w;
    }
    __syncthreads();

    for (int kt = ktb_i; kt <= kte; kt++) {
        ushort4 kreg[4], vreg[4];
        const bool pf = (kt < kte);
        if (pf) {
#pragma unroll
            for (int i = 0; i < 4; i++) {
                const size_t src =
                    hb + (size_t)((kt + 1) * 64 + srow[i]) * C3 + sd0[i];
                kreg[i] = *(const ushort4*)&qkv[src + N_EMBD];
                vreg[i] = *(const ushort4*)&qkv[src + 2 * N_EMBD];
            }
        }

        attn_tile_step(aq0, aq1, Ks, Vt, QPs, m_row, l_row, acc,
                       qrow, kt, kt == qt, qs2, alibi_q, skb16, skq4,
                       w, quad, l16, lane);
        __syncthreads();

        if (pf) {
#pragma unroll
            for (int i = 0; i < 4; i++) {
                *(ushort4*)&Ks[srow[i]][sd0[i]] = kreg[i];
                Vt[sd0[i] + 0][svr[i]] = vreg[i].x;
                Vt[sd0[i] + 1][svr[i]] = vreg[i].y;
                Vt[sd0[i] + 2][svr[i]] = vreg[i].z;
                Vt[sd0[i] + 3][svr[i]] = vreg[i].w;
            }
        }
        __syncthreads();
    }

    if (!split) {
        const float li = 1.f / l_row;
        float ia[4];
#pragma unroll
        for (int r = 0; r < 4; r++)
            ia[r] = __shfl(li, (lane & 48) + quad * 4 + r);
#pragma unroll
        for (int r = 0; r < 4; r++) {
            const int qa = q0 + w * 16 + quad * 4 + r;
#pragma unroll
            for (int db = 0; db < 4; db++) {
                y[((size_t)b * T + qa) * N_EMBD + h * HEAD_D + db * 16 + l16] =
                    f2b(acc[db][r] * ia[r]);
            }
        }
    } else {
        const int pidx = (bh * 16 + (qt - 16)) * 2 + cc;
#pragma unroll
        for (int r = 0; r < 4; r++) {
            const int row = w * 16 + quad * 4 + r;
#pragma unroll
            for (int db = 0; db < 4; db++) {
                opart[((size_t)pidx * 64 + row) * 64 + db * 16 + l16] =
                    acc[db][r];
            }
        }
        if (quad == 0) {
            mpart[pidx * 64 + w * 16 + l16] = m_row;
            lpart[pidx * 64 + w * 16 + l16] = l_row;
        }
    }
}

// ---------------------------------------------------------------------------
// Attention combine: merge the 2 KV-half partials for each split q-tile.
// ---------------------------------------------------------------------------
__global__ __launch_bounds__(256) void attn_combine_kernel(
        const float* __restrict__ opart, const float* __restrict__ mpart,
        const float* __restrict__ lpart, ushort* __restrict__ y, int T) {
    const int x  = blockIdx.x;
    const int bh = x >> 4;
    const int qt = 16 + (x & 15);
    const int b  = bh >> 4, h = bh & 15;
    const int t  = threadIdx.x;
    const int row = t >> 2;
    const int dq  = (t & 3) << 4;
    const int p0 = x * 2, p1 = p0 + 1;

    const float m0 = mpart[p0 * 64 + row], m1 = mpart[p1 * 64 + row];
    const float l0 = lpart[p0 * 64 + row], l1 = lpart[p1 * 64 + row];
    const float M  = fmaxf(m0, m1);
    const float w0 = exp2f(m0 - M), w1 = exp2f(m1 - M);
    const float inv = 1.f / (l0 * w0 + l1 * w1);

    const float* o0 = &opart[((size_t)p0 * 64 + row) * 64 + dq];
    const float* o1 = &opart[((size_t)p1 * 64 + row) * 64 + dq];
    ushort* yr = &y[((size_t)b * T + qt * 64 + row) * N_EMBD + h * HEAD_D + dq];
#pragma unroll
    for (int j = 0; j < 16; j += 4) {
        const float4 a = *(const float4*)&o0[j];
        const float4 c = *(const float4*)&o1[j];
        yr[j + 0] = f2b((a.x * w0 + c.x * w1) * inv);
        yr[j + 1] = f2b((a.y * w0 + c.y * w1) * inv);
        yr[j + 2] = f2b((a.z * w0 + c.z * w1) * inv);
        yr[j + 3] = f2b((a.w * w0 + c.w * w1) * inv);
    }
}

// ---------------------------------------------------------------------------
extern "C" void kernel_launch(void* const* d_in, const int* in_sizes, int n_in,
                              void* d_out, int out_size, void* d_ws, size_t ws_size,
                              hipStream_t stream) {
    const int B = 2, T = 2048, C = N_EMBD;
    const int M = B * T;

    const float* x      = (const float*)d_in[0];
    const float* ln1_w  = (const float*)d_in[1];
    const float* ln1_b  = (const float*)d_in[2];
    const float* w_qkv  = (const float*)d_in[3];
    const float* b_qkv  = (const float*)d_in[4];
    const float* w_proj = (const float*)d_in[5];
    const float* b_proj = (const float*)d_in[6];
    const float* ln2_w  = (const float*)d_in[7];
    const float* ln2_b  = (const float*)d_in[8];
    const float* w_fc   = (const float*)d_in[9];
    const float* b_fc   = (const float*)d_in[10];
    const float* w_fc2  = (const float*)d_in[11];
    const float* b_fc2  = (const float*)d_in[12];
    float* out = (float*)d_out;

    char* ws = (char*)d_ws;
    size_t off = 0;
    ushort* wt_qkv  = (ushort*)(ws + off); off += (size_t)3 * C * C * 2;
    ushort* wt_proj = (ushort*)(ws + off); off += (size_t)C * C * 2;
    ushort* wt_fc   = (ushort*)(ws + off); off += (size_t)4 * C * C * 2;
    ushort* wt_fc2  = (ushort*)(ws + off); off += (size_t)4 * C * C * 2;
    ushort* h16     = (ushort*)(ws + off); off += (size_t)M * C * 2;
    ushort* qkv16   = (ushort*)(ws + off); off += (size_t)M * 3 * C * 2;
    ushort* y16     = (ushort*)(ws + off); off += (size_t)M * C * 2;
    ushort* fc16    = (ushort*)(ws + off); off += (size_t)M * 4 * C * 2;

    // 0. weight transpose+convert
    convtrans_kernel<<<dim3(3 * C / 32, C / 32), 256, 0, stream>>>(w_qkv, wt_qkv, C, 3 * C);
    convtrans_kernel<<<dim3(C / 32, C / 32), 256, 0, stream>>>(w_proj, wt_proj, C, C);
    convtrans_kernel<<<dim3(4 * C / 32, C / 32), 256, 0, stream>>>(w_fc, wt_fc, C, 4 * C);
    convtrans_kernel<<<dim3(C / 32, 4 * C / 32), 256, 0, stream>>>(w_fc2, wt_fc2, 4 * C, C);

    // 1. h = LN1(x) -> bf16
    ln_kernel<<<M, 256, 0, stream>>>(x, ln1_w, ln1_b, h16);

    // 2. qkv = h @ w_qkv + b_qkv -> bf16  (256^2 tiles)
    gemm256_bf16_kernel<<<dim3(3 * C / 256, M / 256), 512, 0, stream>>>(
        h16, wt_qkv, b_qkv, nullptr, nullptr, qkv16, M, 3 * C, C, 0);

    // 3. flash ALiBi attention, KV-split long tiles; partials in fc16 region.
    float* aop = (float*)fc16;
    float* amp = aop + (size_t)1024 * 64 * 64;
    float* alp = amp + (size_t)1024 * 64;
    attn_mfma_kernel<<<32 * 48, 256, 0, stream>>>(
        qkv16, y16, aop, amp, alp, B, T);
    attn_combine_kernel<<<512, 256, 0, stream>>>(aop, amp, alp, y16, T);

    // 4. x1 = x + y @ w_proj + b_proj -> d_out (fp32)  (128^2, N small)
    gemm_bf16_kernel<<<dim3(C / 128, M / 128), 256, 0, stream>>>(
        y16, wt_proj, b_proj, x, out, nullptr, M, C, C, 0);

    // 5. h = LN2(x1) -> bf16
    ln_kernel<<<M, 256, 0, stream>>>(out, ln2_w, ln2_b, h16);

    // 6. fc = gelu(h @ w_fc + b_fc) -> bf16  (256^2 tiles)
    gemm256_bf16_kernel<<<dim3(4 * C / 256, M / 256), 512, 0, stream>>>(
        h16, wt_fc, b_fc, nullptr, nullptr, fc16, M, 4 * C, C, 1);

    // 7. fc2 split-K=2 (256^2 tiles) + combine
    float* part = (float*)h16;
    gemm256_bf16_kernel<<<dim3(C / 256, M / 256, 2), 512, 0, stream>>>(
        fc16, wt_fc2, nullptr, nullptr, part, nullptr, M, C, 4 * C, 0);
    combine_kernel<<<(M * C) / (256 * 4), 256, 0, stream>>>(
        part, part + (size_t)M * C, b_fc2, out);
}

// Round 10
// 447.330 us; speedup vs baseline: 1.0046x; 1.0046x over previous
//
#include <hip/hip_runtime.h>
#include <hip/hip_bf16.h>
#include <math.h>

#define N_EMBD 1024
#define N_HEADC 16
#define HEAD_D 64

typedef __attribute__((ext_vector_type(8))) short short8;
typedef __attribute__((ext_vector_type(4))) float floatx4;

__device__ __forceinline__ ushort f2b(float f) {
    __hip_bfloat16 h = __float2bfloat16(f);
    return *reinterpret_cast<ushort*>(&h);
}

__device__ __forceinline__ void async_cp16(const void* gsrc, void* ldst) {
    __builtin_amdgcn_global_load_lds(
        (const __attribute__((address_space(1))) void*)gsrc,
        (__attribute__((address_space(3))) void*)ldst, 16, 0, 0);
}

// Bijective XCD-chunk swizzle (m204 form).
__device__ __forceinline__ int xcd_swizzle(int bid, int nwg) {
    const int q = nwg >> 3, r = nwg & 7;
    const int xcd = bid & 7, loc = bid >> 3;
    return (xcd < r ? xcd * (q + 1) : r * (q + 1) + (xcd - r) * q) + loc;
}

// ---------------------------------------------------------------------------
// LayerNorm: fp32 in, bf16 out. One block (256 thr) per row of C=1024.
// ---------------------------------------------------------------------------
__global__ __launch_bounds__(256) void ln_kernel(const float* __restrict__ x,
                                                 const float* __restrict__ w,
                                                 const float* __restrict__ b,
                                                 ushort* __restrict__ out) {
    const int row = blockIdx.x;
    const int t = threadIdx.x;
    const float4 v = reinterpret_cast<const float4*>(x + (size_t)row * N_EMBD)[t];
    float s  = v.x + v.y + v.z + v.w;
    float ss = v.x * v.x + v.y * v.y + v.z * v.z + v.w * v.w;
    for (int o = 32; o > 0; o >>= 1) {
        s  += __shfl_down(s, o);
        ss += __shfl_down(ss, o);
    }
    __shared__ float as_[4], ass_[4];
    const int wid = t >> 6, lane = t & 63;
    if (lane == 0) { as_[wid] = s; ass_[wid] = ss; }
    __syncthreads();
    const float ts  = as_[0] + as_[1] + as_[2] + as_[3];
    const float tss = ass_[0] + ass_[1] + ass_[2] + ass_[3];
    const float mu  = ts * (1.f / N_EMBD);
    const float var = tss * (1.f / N_EMBD) - mu * mu;
    const float inv = rsqrtf(var + 1e-5f);
    const float4 wv = reinterpret_cast<const float4*>(w)[t];
    const float4 bv = reinterpret_cast<const float4*>(b)[t];
    ushort4 o;
    o.x = f2b((v.x - mu) * inv * wv.x + bv.x);
    o.y = f2b((v.y - mu) * inv * wv.y + bv.y);
    o.z = f2b((v.z - mu) * inv * wv.z + bv.z);
    o.w = f2b((v.w - mu) * inv * wv.w + bv.w);
    reinterpret_cast<ushort4*>(out + (size_t)row * N_EMBD)[t] = o;
}

// ---------------------------------------------------------------------------
// Transpose + convert: W[K,N] fp32 -> Wt[N,K] bf16. 32x32 tiles, 256 thr.
// ---------------------------------------------------------------------------
__global__ void convtrans_kernel(const float* __restrict__ W,
                                 ushort* __restrict__ Wt, int K, int N) {
    __shared__ float tile[32][33];
    const int tid = threadIdx.x;
    const int r = tid >> 3;
    const int c4 = (tid & 7) * 4;
    const int bx = blockIdx.x, by = blockIdx.y;

    float4 v = *(const float4*)&W[((size_t)(by * 32 + r)) * N + bx * 32 + c4];
    tile[r][c4 + 0] = v.x; tile[r][c4 + 1] = v.y;
    tile[r][c4 + 2] = v.z; tile[r][c4 + 3] = v.w;
    __syncthreads();

    ushort4 u;
    u.x = f2b(tile[c4 + 0][r]); u.y = f2b(tile[c4 + 1][r]);
    u.z = f2b(tile[c4 + 2][r]); u.w = f2b(tile[c4 + 3][r]);
    *(ushort4*)&Wt[((size_t)(bx * 32 + r)) * K + by * 32 + c4] = u;
}

// ---------------------------------------------------------------------------
// 128^2 bf16 MFMA GEMM: counted-vmcnt double buffer (R7 structure, the
// verified 409us state). Optional split-K: atomic_out accumulates partials
// directly into out32 (which must be pre-filled with the residual term).
// ---------------------------------------------------------------------------
__device__ __forceinline__ void gemm_stage(
        const ushort* __restrict__ A, const ushort* __restrict__ Bt,
        ushort* As, ushort* Bs,
        int m0, int n0, int K, int k0, int w, int lane) {
#pragma unroll
    for (int l = 0; l < 2; l++) {
        const int cbase = w * 128 + l * 64;
        const int c = cbase + lane;
        const int row = c >> 2, kc8 = (c & 3) * 8;
        async_cp16(A  + (size_t)(m0 + row) * K + k0 + kc8, &As[cbase * 8]);
        async_cp16(Bt + (size_t)(n0 + row) * K + k0 + kc8, &Bs[cbase * 8]);
    }
}
// one stage = 4 global_load_lds per wave -> vmcnt quantum is 4.

__device__ __forceinline__ void gemm_compute(
        const ushort* As, const ushort* Bs, floatx4 (*acc)[4],
        int wm, int wn, int quad, int l16) {
    short8 a[4], bf[4];
#pragma unroll
    for (int i = 0; i < 4; i++)
        a[i] = *(const short8*)&As[(wm * 64 + i * 16 + l16) * 32 + quad * 8];
#pragma unroll
    for (int j = 0; j < 4; j++)
        bf[j] = *(const short8*)&Bs[(wn * 64 + j * 16 + l16) * 32 + quad * 8];
#pragma unroll
    for (int i = 0; i < 4; i++)
#pragma unroll
        for (int j = 0; j < 4; j++)
            acc[i][j] = __builtin_amdgcn_mfma_f32_16x16x32_bf16(
                a[i], bf[j], acc[i][j], 0, 0, 0);
}

__global__ __launch_bounds__(256) void gemm_bf16_kernel(
        const ushort* __restrict__ A,
        const ushort* __restrict__ Bt,
        const float* __restrict__ bias,
        const float* __restrict__ residual,
        float* __restrict__ out32,
        ushort* __restrict__ out16,
        int M, int N, int K, int do_gelu, int atomic_out) {
    __shared__ ushort As[2][128 * 32];
    __shared__ ushort Bs[2][128 * 32];

    const int tid  = threadIdx.x;
    const int w    = tid >> 6;
    const int lane = tid & 63;
    const int quad = lane >> 4;
    const int l16  = lane & 15;
    const int wm   = w >> 1;
    const int wn   = w & 1;

    int bid = blockIdx.y * gridDim.x + blockIdx.x;
    bid = xcd_swizzle(bid, gridDim.x * gridDim.y);
    const int bx = bid % gridDim.x;
    const int by = bid / gridDim.x;
    const int m0 = by * 128;
    const int n0 = bx * 128;

    const int kchunk = K / gridDim.z;
    const int kbeg   = blockIdx.z * kchunk;

    floatx4 acc[4][4];
#pragma unroll
    for (int i = 0; i < 4; i++)
#pragma unroll
        for (int j = 0; j < 4; j++) acc[i][j] = (floatx4){0.f, 0.f, 0.f, 0.f};

    const int nt = kchunk >> 5;

    gemm_stage(A, Bt, As[0], Bs[0], m0, n0, K, kbeg, w, lane);
    gemm_stage(A, Bt, As[1], Bs[1], m0, n0, K, kbeg + 32, w, lane);

    for (int t = 0; t < nt; t++) {
        if (t + 1 < nt) {
            asm volatile("s_waitcnt vmcnt(4)" ::: "memory");
        } else {
            asm volatile("s_waitcnt vmcnt(0)" ::: "memory");
        }
        __builtin_amdgcn_sched_barrier(0);
        __builtin_amdgcn_s_barrier();

        gemm_compute(As[t & 1], Bs[t & 1], acc, wm, wn, quad, l16);

        __builtin_amdgcn_s_barrier();
        if (t + 2 < nt)
            gemm_stage(A, Bt, As[t & 1], Bs[t & 1],
                       m0, n0, K, kbeg + ((t + 2) << 5), w, lane);
    }

    const int addb = (!atomic_out || blockIdx.z == 0) ? 1 : 0;
#pragma unroll
    for (int i = 0; i < 4; i++) {
#pragma unroll
        for (int j = 0; j < 4; j++) {
            const int nn = n0 + wn * 64 + j * 16 + l16;
            const float bv = (bias && addb) ? bias[nn] : 0.f;
#pragma unroll
            for (int r = 0; r < 4; r++) {
                const int mm = m0 + wm * 64 + i * 16 + quad * 4 + r;
                float v = acc[i][j][r] + bv;
                if (do_gelu) v = 0.5f * v * (1.f + erff(v * 0.70710678118654752f));
                if (residual) v += residual[(size_t)mm * N + nn];
                if (atomic_out) {
                    atomicAdd(&out32[(size_t)mm * N + nn], v);
                } else {
                    if (out32) out32[(size_t)mm * N + nn] = v;
                    if (out16) out16[(size_t)mm * N + nn] = f2b(v);
                }
            }
        }
    }
}

// ---------------------------------------------------------------------------
// Flash ALiBi attention, SWAPPED QK^T (unchanged from R6/R7).
// ---------------------------------------------------------------------------
#define AT_PAD 72
#define LOG2E 1.4426950408889634f

__device__ __forceinline__ void attn_tile_step(
        short8 aq0, short8 aq1,
        ushort (*__restrict__ Ks)[AT_PAD],
        ushort (*__restrict__ Vt)[AT_PAD],
        ushort (*__restrict__ Ps)[AT_PAD],
        float& m_row, float& l_row, floatx4* acc,
        int qrow, int kt, bool domask,
        float qs2, float alibi_q, float skb16, const float* skq4,
        int w, int quad, int l16, int lane) {
    floatx4 sfrag[4];
#pragma unroll
    for (int kb = 0; kb < 4; kb++) {
        const int krow = kb * 16 + l16;
        short8 ak0 = *(const short8*)&Ks[krow][quad * 8];
        short8 ak1 = *(const short8*)&Ks[krow][32 + quad * 8];
        floatx4 s = (floatx4){0.f, 0.f, 0.f, 0.f};
        s = __builtin_amdgcn_mfma_f32_16x16x32_bf16(ak0, aq0, s, 0, 0, 0);
        s = __builtin_amdgcn_mfma_f32_16x16x32_bf16(ak1, aq1, s, 0, 0, 0);
        sfrag[kb] = s;
    }

    const float rowc = alibi_q - skb16 * (float)(kt * 4);
    float sv[4][4];
    float rm = -INFINITY;
#pragma unroll
    for (int kb = 0; kb < 4; kb++) {
        const float rck = rowc - skb16 * (float)kb;
#pragma unroll
        for (int r = 0; r < 4; r++) {
            float s = fmaf(sfrag[kb][r], qs2, rck - skq4[r]);
            if (domask) {
                const int k = kt * 64 + kb * 16 + quad * 4 + r;
                s = (k <= qrow) ? s : -INFINITY;
            }
            sv[kb][r] = s;
            rm = fmaxf(rm, s);
        }
    }
    rm = fmaxf(rm, __shfl_xor(rm, 16));
    rm = fmaxf(rm, __shfl_xor(rm, 32));

    if (__any(rm > m_row)) {
        const float mn = fmaxf(rm, m_row);
        const float corr = exp2f(m_row - mn);
        m_row = mn;
        l_row *= corr;
        float cr[4];
#pragma unroll
        for (int r = 0; r < 4; r++)
            cr[r] = __shfl(corr, (lane & 48) + quad * 4 + r);
#pragma unroll
        for (int db = 0; db < 4; db++)
#pragma unroll
            for (int r = 0; r < 4; r++) acc[db][r] *= cr[r];
    }

    float rs = 0.f;
#pragma unroll
    for (int kb = 0; kb < 4; kb++) {
        const float p0 = exp2f(sv[kb][0] - m_row);
        const float p1 = exp2f(sv[kb][1] - m_row);
        const float p2 = exp2f(sv[kb][2] - m_row);
        const float p3 = exp2f(sv[kb][3] - m_row);
        rs += (p0 + p1) + (p2 + p3);
        ushort4 pw;
        pw.x = f2b(p0); pw.y = f2b(p1); pw.z = f2b(p2); pw.w = f2b(p3);
        *(ushort4*)&Ps[w * 16 + l16][kb * 16 + quad * 4] = pw;
    }
    rs += __shfl_xor(rs, 16);
    rs += __shfl_xor(rs, 32);
    l_row += rs;

    short8 ap0 = *(const short8*)&Ps[w * 16 + l16][quad * 8];
    short8 ap1 = *(const short8*)&Ps[w * 16 + l16][32 + quad * 8];
#pragma unroll
    for (int db = 0; db < 4; db++) {
        const int dv = db * 16 + l16;
        const int svw = ((db * 4 + (l16 >> 2)) & 7) << 3;
        short8 bv0 = *(const short8*)&Vt[dv][(quad * 8) ^ svw];
        short8 bv1 = *(const short8*)&Vt[dv][(32 + quad * 8) ^ svw];
        acc[db] = __builtin_amdgcn_mfma_f32_16x16x32_bf16(ap0, bv0, acc[db], 0, 0, 0);
        acc[db] = __builtin_amdgcn_mfma_f32_16x16x32_bf16(ap1, bv1, acc[db], 0, 0, 0);
    }
}

__global__ __launch_bounds__(256) void attn_mfma_kernel(
        const ushort* __restrict__ qkv, ushort* __restrict__ y,
        float* __restrict__ opart, float* __restrict__ mpart,
        float* __restrict__ lpart, int B, int T) {
    const int C3 = 3 * N_EMBD;

    const int lin = xcd_swizzle(blockIdx.x, gridDim.x);
    const int bh = lin / 48;
    const int s  = lin % 48;
    int qt, cc, ktb_i, kte;
    bool split;
    if (s < 32) {
        split = true;
        qt = 31 - (s >> 1);
        cc = s & 1;
        const int hc = (qt + 2) >> 1;
        ktb_i = cc ? hc : 0;
        kte   = cc ? qt : hc - 1;
    } else {
        split = false;
        qt = 47 - s;
        cc = 0;
        ktb_i = 0;
        kte = qt;
    }
    const int b = bh >> 4, h = bh & 15;

    const int tid  = threadIdx.x;
    const int lane = tid & 63;
    const int w    = tid >> 6;
    const int quad = lane >> 4;
    const int l16  = lane & 15;

    __shared__ ushort QPs[64][AT_PAD];
    __shared__ ushort Ks[64][AT_PAD];
    __shared__ ushort Vt[64][AT_PAD];

    const float slope  = exp2f(-0.5f * (float)(h + 1));
    const float slope2 = slope * LOG2E;
    const float qs2    = 0.125f * LOG2E;

    const int q0 = qt * 64;
    const int qrow = q0 + w * 16 + l16;
    const float alibi_q = slope2 * (float)qrow;
    const float skb16   = slope2 * 16.f;
    float skq4[4];
#pragma unroll
    for (int r = 0; r < 4; r++) skq4[r] = slope2 * (float)(quad * 4 + r);

    const size_t hb = (size_t)b * T * C3 + (size_t)h * HEAD_D;

    int srow[4], sd0[4], svr[4];
#pragma unroll
    for (int i = 0; i < 4; i++) {
        const int idx = tid + i * 256;
        srow[i] = idx >> 4;
        sd0[i]  = (idx & 15) * 4;
        svr[i]  = srow[i] ^ ((idx & 7) << 3);
    }

#pragma unroll
    for (int i = 0; i < 4; i++) {
        *(ushort4*)&QPs[srow[i]][sd0[i]] =
            *(const ushort4*)&qkv[hb + (size_t)(q0 + srow[i]) * C3 + sd0[i]];
    }
    __syncthreads();

    const int mrow = w * 16 + l16;
    short8 aq0 = *(const short8*)&QPs[mrow][quad * 8];
    short8 aq1 = *(const short8*)&QPs[mrow][32 + quad * 8];

    float m_row = -INFINITY, l_row = 0.f;
    floatx4 acc[4];
#pragma unroll
    for (int r = 0; r < 4; r++) acc[r] = (floatx4){0.f, 0.f, 0.f, 0.f};

#pragma unroll
    for (int i = 0; i < 4; i++) {
        const size_t src = hb + (size_t)(ktb_i * 64 + srow[i]) * C3 + sd0[i];
        *(ushort4*)&Ks[srow[i]][sd0[i]] = *(const ushort4*)&qkv[src + N_EMBD];
        ushort4 vv = *(const ushort4*)&qkv[src + 2 * N_EMBD];
        Vt[sd0[i] + 0][svr[i]] = vv.x;
        Vt[sd0[i] + 1][svr[i]] = vv.y;
        Vt[sd0[i] + 2][svr[i]] = vv.z;
        Vt[sd0[i] + 3][svr[i]] = vv.w;
    }
    __syncthreads();

    for (int kt = ktb_i; kt <= kte; kt++) {
        ushort4 kreg[4], vreg[4];
        const bool pf = (kt < kte);
        if (pf) {
#pragma unroll
            for (int i = 0; i < 4; i++) {
                const size_t src =
                    hb + (size_t)((kt + 1) * 64 + srow[i]) * C3 + sd0[i];
                kreg[i] = *(const ushort4*)&qkv[src + N_EMBD];
                vreg[i] = *(const ushort4*)&qkv[src + 2 * N_EMBD];
            }
        }

        attn_tile_step(aq0, aq1, Ks, Vt, QPs, m_row, l_row, acc,
                       qrow, kt, kt == qt, qs2, alibi_q, skb16, skq4,
                       w, quad, l16, lane);
        __syncthreads();

        if (pf) {
#pragma unroll
            for (int i = 0; i < 4; i++) {
                *(ushort4*)&Ks[srow[i]][sd0[i]] = kreg[i];
                Vt[sd0[i] + 0][svr[i]] = vreg[i].x;
                Vt[sd0[i] + 1][svr[i]] = vreg[i].y;
                Vt[sd0[i] + 2][svr[i]] = vreg[i].z;
                Vt[sd0[i] + 3][svr[i]] = vreg[i].w;
            }
        }
        __syncthreads();
    }

    if (!split) {
        const float li = 1.f / l_row;
        float ia[4];
#pragma unroll
        for (int r = 0; r < 4; r++)
            ia[r] = __shfl(li, (lane & 48) + quad * 4 + r);
#pragma unroll
        for (int r = 0; r < 4; r++) {
            const int qa = q0 + w * 16 + quad * 4 + r;
#pragma unroll
            for (int db = 0; db < 4; db++) {
                y[((size_t)b * T + qa) * N_EMBD + h * HEAD_D + db * 16 + l16] =
                    f2b(acc[db][r] * ia[r]);
            }
        }
    } else {
        const int pidx = (bh * 16 + (qt - 16)) * 2 + cc;
#pragma unroll
        for (int r = 0; r < 4; r++) {
            const int row = w * 16 + quad * 4 + r;
#pragma unroll
            for (int db = 0; db < 4; db++) {
                opart[((size_t)pidx * 64 + row) * 64 + db * 16 + l16] =
                    acc[db][r];
            }
        }
        if (quad == 0) {
            mpart[pidx * 64 + w * 16 + l16] = m_row;
            lpart[pidx * 64 + w * 16 + l16] = l_row;
        }
    }
}

// ---------------------------------------------------------------------------
// Attention combine: merge the 2 KV-half partials for each split q-tile.
// ---------------------------------------------------------------------------
__global__ __launch_bounds__(256) void attn_combine_kernel(
        const float* __restrict__ opart, const float* __restrict__ mpart,
        const float* __restrict__ lpart, ushort* __restrict__ y, int T) {
    const int x  = blockIdx.x;
    const int bh = x >> 4;
    const int qt = 16 + (x & 15);
    const int b  = bh >> 4, h = bh & 15;
    const int t  = threadIdx.x;
    const int row = t >> 2;
    const int dq  = (t & 3) << 4;
    const int p0 = x * 2, p1 = p0 + 1;

    const float m0 = mpart[p0 * 64 + row], m1 = mpart[p1 * 64 + row];
    const float l0 = lpart[p0 * 64 + row], l1 = lpart[p1 * 64 + row];
    const float M  = fmaxf(m0, m1);
    const float w0 = exp2f(m0 - M), w1 = exp2f(m1 - M);
    const float inv = 1.f / (l0 * w0 + l1 * w1);

    const float* o0 = &opart[((size_t)p0 * 64 + row) * 64 + dq];
    const float* o1 = &opart[((size_t)p1 * 64 + row) * 64 + dq];
    ushort* yr = &y[((size_t)b * T + qt * 64 + row) * N_EMBD + h * HEAD_D + dq];
#pragma unroll
    for (int j = 0; j < 16; j += 4) {
        const float4 a = *(const float4*)&o0[j];
        const float4 c = *(const float4*)&o1[j];
        yr[j + 0] = f2b((a.x * w0 + c.x * w1) * inv);
        yr[j + 1] = f2b((a.y * w0 + c.y * w1) * inv);
        yr[j + 2] = f2b((a.z * w0 + c.z * w1) * inv);
        yr[j + 3] = f2b((a.w * w0 + c.w * w1) * inv);
    }
}

// ---------------------------------------------------------------------------
extern "C" void kernel_launch(void* const* d_in, const int* in_sizes, int n_in,
                              void* d_out, int out_size, void* d_ws, size_t ws_size,
                              hipStream_t stream) {
    const int B = 2, T = 2048, C = N_EMBD;
    const int M = B * T;

    const float* x      = (const float*)d_in[0];
    const float* ln1_w  = (const float*)d_in[1];
    const float* ln1_b  = (const float*)d_in[2];
    const float* w_qkv  = (const float*)d_in[3];
    const float* b_qkv  = (const float*)d_in[4];
    const float* w_proj = (const float*)d_in[5];
    const float* b_proj = (const float*)d_in[6];
    const float* ln2_w  = (const float*)d_in[7];
    const float* ln2_b  = (const float*)d_in[8];
    const float* w_fc   = (const float*)d_in[9];
    const float* b_fc   = (const float*)d_in[10];
    const float* w_fc2  = (const float*)d_in[11];
    const float* b_fc2  = (const float*)d_in[12];
    float* out = (float*)d_out;

    char* ws = (char*)d_ws;
    size_t off = 0;
    ushort* wt_qkv  = (ushort*)(ws + off); off += (size_t)3 * C * C * 2;
    ushort* wt_proj = (ushort*)(ws + off); off += (size_t)C * C * 2;
    ushort* wt_fc   = (ushort*)(ws + off); off += (size_t)4 * C * C * 2;
    ushort* wt_fc2  = (ushort*)(ws + off); off += (size_t)4 * C * C * 2;
    ushort* h16     = (ushort*)(ws + off); off += (size_t)M * C * 2;
    ushort* qkv16   = (ushort*)(ws + off); off += (size_t)M * 3 * C * 2;
    ushort* y16     = (ushort*)(ws + off); off += (size_t)M * C * 2;
    ushort* fc16    = (ushort*)(ws + off); off += (size_t)M * 4 * C * 2;

    // 0. weight transpose+convert
    convtrans_kernel<<<dim3(3 * C / 32, C / 32), 256, 0, stream>>>(w_qkv, wt_qkv, C, 3 * C);
    convtrans_kernel<<<dim3(C / 32, C / 32), 256, 0, stream>>>(w_proj, wt_proj, C, C);
    convtrans_kernel<<<dim3(4 * C / 32, C / 32), 256, 0, stream>>>(w_fc, wt_fc, C, 4 * C);
    convtrans_kernel<<<dim3(C / 32, 4 * C / 32), 256, 0, stream>>>(w_fc2, wt_fc2, 4 * C, C);

    // 1. h = LN1(x) -> bf16
    ln_kernel<<<M, 256, 0, stream>>>(x, ln1_w, ln1_b, h16);

    // 2. qkv = h @ w_qkv + b_qkv -> bf16
    gemm_bf16_kernel<<<dim3(3 * C / 128, M / 128), 256, 0, stream>>>(
        h16, wt_qkv, b_qkv, nullptr, nullptr, qkv16, M, 3 * C, C, 0, 0);

    // 3. flash ALiBi attention, KV-split long tiles; partials in fc16 region.
    float* aop = (float*)fc16;
    float* amp = aop + (size_t)1024 * 64 * 64;
    float* alp = amp + (size_t)1024 * 64;
    attn_mfma_kernel<<<32 * 48, 256, 0, stream>>>(
        qkv16, y16, aop, amp, alp, B, T);
    attn_combine_kernel<<<512, 256, 0, stream>>>(aop, amp, alp, y16, T);

    // 4. x1 = x + y @ w_proj + b_proj -> d_out (fp32)
    gemm_bf16_kernel<<<dim3(C / 128, M / 128), 256, 0, stream>>>(
        y16, wt_proj, b_proj, x, out, nullptr, M, C, C, 0, 0);

    // 5. h = LN2(x1) -> bf16
    ln_kernel<<<M, 256, 0, stream>>>(out, ln2_w, ln2_b, h16);

    // 6. fc = gelu(h @ w_fc + b_fc) -> bf16
    gemm_bf16_kernel<<<dim3(4 * C / 128, M / 128), 256, 0, stream>>>(
        h16, wt_fc, b_fc, nullptr, nullptr, fc16, M, 4 * C, C, 1, 0);

    // 7. fc2 split-K=4, atomic accumulation into out (already holds x1).
    //    z==0 adds bias; no partial buffers, no combine pass.
    gemm_bf16_kernel<<<dim3(C / 128, M / 128, 4), 256, 0, stream>>>(
        fc16, wt_fc2, b_fc2, nullptr, out, nullptr, M, C, 4 * C, 0, 1);
}

// Round 11
// 396.355 us; speedup vs baseline: 1.1339x; 1.1286x over previous
//
#include <hip/hip_runtime.h>
#include <hip/hip_bf16.h>
#include <math.h>

#define N_EMBD 1024
#define N_HEADC 16
#define HEAD_D 64

typedef __attribute__((ext_vector_type(8))) short short8;
typedef __attribute__((ext_vector_type(4))) float floatx4;

__device__ __forceinline__ ushort f2b(float f) {
    __hip_bfloat16 h = __float2bfloat16(f);
    return *reinterpret_cast<ushort*>(&h);
}

__device__ __forceinline__ void async_cp16(const void* gsrc, void* ldst) {
    __builtin_amdgcn_global_load_lds(
        (const __attribute__((address_space(1))) void*)gsrc,
        (__attribute__((address_space(3))) void*)ldst, 16, 0, 0);
}

// Bijective XCD-chunk swizzle (m204 form).
__device__ __forceinline__ int xcd_swizzle(int bid, int nwg) {
    const int q = nwg >> 3, r = nwg & 7;
    const int xcd = bid & 7, loc = bid >> 3;
    return (xcd < r ? xcd * (q + 1) : r * (q + 1) + (xcd - r) * q) + loc;
}

// ---------------------------------------------------------------------------
// LayerNorm: fp32 in, bf16 out. One block (256 thr) per row of C=1024.
// ---------------------------------------------------------------------------
__global__ __launch_bounds__(256) void ln_kernel(const float* __restrict__ x,
                                                 const float* __restrict__ w,
                                                 const float* __restrict__ b,
                                                 ushort* __restrict__ out) {
    const int row = blockIdx.x;
    const int t = threadIdx.x;
    const float4 v = reinterpret_cast<const float4*>(x + (size_t)row * N_EMBD)[t];
    float s  = v.x + v.y + v.z + v.w;
    float ss = v.x * v.x + v.y * v.y + v.z * v.z + v.w * v.w;
    for (int o = 32; o > 0; o >>= 1) {
        s  += __shfl_down(s, o);
        ss += __shfl_down(ss, o);
    }
    __shared__ float as_[4], ass_[4];
    const int wid = t >> 6, lane = t & 63;
    if (lane == 0) { as_[wid] = s; ass_[wid] = ss; }
    __syncthreads();
    const float ts  = as_[0] + as_[1] + as_[2] + as_[3];
    const float tss = ass_[0] + ass_[1] + ass_[2] + ass_[3];
    const float mu  = ts * (1.f / N_EMBD);
    const float var = tss * (1.f / N_EMBD) - mu * mu;
    const float inv = rsqrtf(var + 1e-5f);
    const float4 wv = reinterpret_cast<const float4*>(w)[t];
    const float4 bv = reinterpret_cast<const float4*>(b)[t];
    ushort4 o;
    o.x = f2b((v.x - mu) * inv * wv.x + bv.x);
    o.y = f2b((v.y - mu) * inv * wv.y + bv.y);
    o.z = f2b((v.z - mu) * inv * wv.z + bv.z);
    o.w = f2b((v.w - mu) * inv * wv.w + bv.w);
    reinterpret_cast<ushort4*>(out + (size_t)row * N_EMBD)[t] = o;
}

// ---------------------------------------------------------------------------
// Transpose + convert: W[K,N] fp32 -> Wt[N,K] bf16. 32x32 tiles, 256 thr.
// ---------------------------------------------------------------------------
__global__ void convtrans_kernel(const float* __restrict__ W,
                                 ushort* __restrict__ Wt, int K, int N) {
    __shared__ float tile[32][33];
    const int tid = threadIdx.x;
    const int r = tid >> 3;
    const int c4 = (tid & 7) * 4;
    const int bx = blockIdx.x, by = blockIdx.y;

    float4 v = *(const float4*)&W[((size_t)(by * 32 + r)) * N + bx * 32 + c4];
    tile[r][c4 + 0] = v.x; tile[r][c4 + 1] = v.y;
    tile[r][c4 + 2] = v.z; tile[r][c4 + 3] = v.w;
    __syncthreads();

    ushort4 u;
    u.x = f2b(tile[c4 + 0][r]); u.y = f2b(tile[c4 + 1][r]);
    u.z = f2b(tile[c4 + 2][r]); u.w = f2b(tile[c4 + 3][r]);
    *(ushort4*)&Wt[((size_t)(bx * 32 + r)) * K + by * 32 + c4] = u;
}

// ---------------------------------------------------------------------------
// 128^2 bf16 MFMA GEMM: counted-vmcnt double buffer (R7 verified structure).
// Optional split-K via gridDim.z: partial z written at out32 + z*M*N.
// ---------------------------------------------------------------------------
__device__ __forceinline__ void gemm_stage(
        const ushort* __restrict__ A, const ushort* __restrict__ Bt,
        ushort* As, ushort* Bs,
        int m0, int n0, int K, int k0, int w, int lane) {
#pragma unroll
    for (int l = 0; l < 2; l++) {
        const int cbase = w * 128 + l * 64;
        const int c = cbase + lane;
        const int row = c >> 2, kc8 = (c & 3) * 8;
        async_cp16(A  + (size_t)(m0 + row) * K + k0 + kc8, &As[cbase * 8]);
        async_cp16(Bt + (size_t)(n0 + row) * K + k0 + kc8, &Bs[cbase * 8]);
    }
}
// one gemm_stage = 4 global_load_lds per wave -> vmcnt quantum is 4.

__device__ __forceinline__ void gemm_compute(
        const ushort* As, const ushort* Bs, floatx4 (*acc)[4],
        int wm, int wn, int quad, int l16) {
    short8 a[4], bf[4];
#pragma unroll
    for (int i = 0; i < 4; i++)
        a[i] = *(const short8*)&As[(wm * 64 + i * 16 + l16) * 32 + quad * 8];
#pragma unroll
    for (int j = 0; j < 4; j++)
        bf[j] = *(const short8*)&Bs[(wn * 64 + j * 16 + l16) * 32 + quad * 8];
#pragma unroll
    for (int i = 0; i < 4; i++)
#pragma unroll
        for (int j = 0; j < 4; j++)
            acc[i][j] = __builtin_amdgcn_mfma_f32_16x16x32_bf16(
                a[i], bf[j], acc[i][j], 0, 0, 0);
}

__device__ __forceinline__ void gemm_epilogue(
        floatx4 (*acc)[4], const float* bias, const float* residual,
        float* out32, ushort* out16, int M, int N,
        int m0, int n0, int wm, int wn, int quad, int l16, int do_gelu) {
#pragma unroll
    for (int i = 0; i < 4; i++) {
#pragma unroll
        for (int j = 0; j < 4; j++) {
            const int nn = n0 + wn * 64 + j * 16 + l16;
            const float bv = bias ? bias[nn] : 0.f;
#pragma unroll
            for (int r = 0; r < 4; r++) {
                const int mm = m0 + wm * 64 + i * 16 + quad * 4 + r;
                float v = acc[i][j][r] + bv;
                if (do_gelu) v = 0.5f * v * (1.f + erff(v * 0.70710678118654752f));
                if (residual) v += residual[(size_t)mm * N + nn];
                if (out32) out32[(size_t)mm * N + nn] = v;
                if (out16) out16[(size_t)mm * N + nn] = f2b(v);
            }
        }
    }
}

__global__ __launch_bounds__(256) void gemm_bf16_kernel(
        const ushort* __restrict__ A,
        const ushort* __restrict__ Bt,
        const float* __restrict__ bias,
        const float* __restrict__ residual,
        float* __restrict__ out32,
        ushort* __restrict__ out16,
        int M, int N, int K, int do_gelu) {
    __shared__ ushort As[2][128 * 32];
    __shared__ ushort Bs[2][128 * 32];

    const int tid  = threadIdx.x;
    const int w    = tid >> 6;
    const int lane = tid & 63;
    const int quad = lane >> 4;
    const int l16  = lane & 15;
    const int wm   = w >> 1;
    const int wn   = w & 1;

    int bid = blockIdx.y * gridDim.x + blockIdx.x;
    bid = xcd_swizzle(bid, gridDim.x * gridDim.y);
    const int bx = bid % gridDim.x;
    const int by = bid / gridDim.x;
    const int m0 = by * 128;
    const int n0 = bx * 128;

    const int kchunk = K / gridDim.z;
    const int kbeg   = blockIdx.z * kchunk;
    if (gridDim.z > 1)
        out32 += (size_t)blockIdx.z * M * N;

    floatx4 acc[4][4];
#pragma unroll
    for (int i = 0; i < 4; i++)
#pragma unroll
        for (int j = 0; j < 4; j++) acc[i][j] = (floatx4){0.f, 0.f, 0.f, 0.f};

    const int nt = kchunk >> 5;

    gemm_stage(A, Bt, As[0], Bs[0], m0, n0, K, kbeg, w, lane);
    gemm_stage(A, Bt, As[1], Bs[1], m0, n0, K, kbeg + 32, w, lane);

    for (int t = 0; t < nt; t++) {
        if (t + 1 < nt) {
            asm volatile("s_waitcnt vmcnt(4)" ::: "memory");
        } else {
            asm volatile("s_waitcnt vmcnt(0)" ::: "memory");
        }
        __builtin_amdgcn_sched_barrier(0);
        __builtin_amdgcn_s_barrier();

        gemm_compute(As[t & 1], Bs[t & 1], acc, wm, wn, quad, l16);

        __builtin_amdgcn_s_barrier();
        if (t + 2 < nt)
            gemm_stage(A, Bt, As[t & 1], Bs[t & 1],
                       m0, n0, K, kbeg + ((t + 2) << 5), w, lane);
    }

    gemm_epilogue(acc, bias, residual, out32, out16, M, N,
                  m0, n0, wm, wn, quad, l16, do_gelu);
}

// ---------------------------------------------------------------------------
// BK=64 variant: two 32-K sub-tiles per step (half the barriers/waits).
// 64 KB LDS dbuf -> 2 blocks/CU, used ONLY where the grid caps at 2/CU
// (fc2 split-K=2: 512 blocks). vmcnt quantum is 8 (2 sub-stages x 4 loads).
// ---------------------------------------------------------------------------
__global__ __launch_bounds__(256) void gemm_bf16_k64_kernel(
        const ushort* __restrict__ A,
        const ushort* __restrict__ Bt,
        float* __restrict__ out32,
        int M, int N, int K) {
    __shared__ ushort As[2][2 * 128 * 32];
    __shared__ ushort Bs[2][2 * 128 * 32];

    const int tid  = threadIdx.x;
    const int w    = tid >> 6;
    const int lane = tid & 63;
    const int quad = lane >> 4;
    const int l16  = lane & 15;
    const int wm   = w >> 1;
    const int wn   = w & 1;

    int bid = blockIdx.y * gridDim.x + blockIdx.x;
    bid = xcd_swizzle(bid, gridDim.x * gridDim.y);
    const int bx = bid % gridDim.x;
    const int by = bid / gridDim.x;
    const int m0 = by * 128;
    const int n0 = bx * 128;

    const int kchunk = K / gridDim.z;
    const int kbeg   = blockIdx.z * kchunk;
    if (gridDim.z > 1)
        out32 += (size_t)blockIdx.z * M * N;

    floatx4 acc[4][4];
#pragma unroll
    for (int i = 0; i < 4; i++)
#pragma unroll
        for (int j = 0; j < 4; j++) acc[i][j] = (floatx4){0.f, 0.f, 0.f, 0.f};

    const int nt = kchunk >> 6;   // K-steps of 64; fc2-split: 2048/64 = 32

    // stage64(b, k0): two 32-K sub-stages = 8 loads/wave
    gemm_stage(A, Bt, As[0],        Bs[0],        m0, n0, K, kbeg,      w, lane);
    gemm_stage(A, Bt, As[0] + 4096, Bs[0] + 4096, m0, n0, K, kbeg + 32, w, lane);
    gemm_stage(A, Bt, As[1],        Bs[1],        m0, n0, K, kbeg + 64, w, lane);
    gemm_stage(A, Bt, As[1] + 4096, Bs[1] + 4096, m0, n0, K, kbeg + 96, w, lane);

    for (int t = 0; t < nt; t++) {
        if (t + 1 < nt) {
            asm volatile("s_waitcnt vmcnt(8)" ::: "memory");
        } else {
            asm volatile("s_waitcnt vmcnt(0)" ::: "memory");
        }
        __builtin_amdgcn_sched_barrier(0);
        __builtin_amdgcn_s_barrier();

        gemm_compute(As[t & 1],        Bs[t & 1],        acc, wm, wn, quad, l16);
        gemm_compute(As[t & 1] + 4096, Bs[t & 1] + 4096, acc, wm, wn, quad, l16);

        __builtin_amdgcn_s_barrier();
        if (t + 2 < nt) {
            const int k2 = kbeg + ((t + 2) << 6);
            gemm_stage(A, Bt, As[t & 1],        Bs[t & 1],        m0, n0, K, k2,      w, lane);
            gemm_stage(A, Bt, As[t & 1] + 4096, Bs[t & 1] + 4096, m0, n0, K, k2 + 32, w, lane);
        }
    }

    gemm_epilogue(acc, nullptr, nullptr, out32, nullptr, M, N,
                  m0, n0, wm, wn, quad, l16, 0);
}

// ---------------------------------------------------------------------------
// Split-K combine: out = res + p0 + p1 + bias. One float4 per thread.
// (res may alias out: each thread reads/writes only its own element.)
// ---------------------------------------------------------------------------
__global__ __launch_bounds__(256) void combine_kernel(
        const float* __restrict__ p0, const float* __restrict__ p1,
        const float* __restrict__ bias, const float* __restrict__ res,
        float* __restrict__ out) {
    const int i = blockIdx.x * 256 + threadIdx.x;
    const float4 a = ((const float4*)p0)[i];
    const float4 c = ((const float4*)p1)[i];
    const float4 bb = ((const float4*)bias)[i & 255];
    const float4 rr = ((const float4*)res)[i];
    float4 o;
    o.x = rr.x + a.x + c.x + bb.x;
    o.y = rr.y + a.y + c.y + bb.y;
    o.z = rr.z + a.z + c.z + bb.z;
    o.w = rr.w + a.w + c.w + bb.w;
    ((float4*)out)[i] = o;
}

// ---------------------------------------------------------------------------
// Flash ALiBi attention, SWAPPED QK^T (unchanged from R6/R7).
// ---------------------------------------------------------------------------
#define AT_PAD 72
#define LOG2E 1.4426950408889634f

__device__ __forceinline__ void attn_tile_step(
        short8 aq0, short8 aq1,
        ushort (*__restrict__ Ks)[AT_PAD],
        ushort (*__restrict__ Vt)[AT_PAD],
        ushort (*__restrict__ Ps)[AT_PAD],
        float& m_row, float& l_row, floatx4* acc,
        int qrow, int kt, bool domask,
        float qs2, float alibi_q, float skb16, const float* skq4,
        int w, int quad, int l16, int lane) {
    floatx4 sfrag[4];
#pragma unroll
    for (int kb = 0; kb < 4; kb++) {
        const int krow = kb * 16 + l16;
        short8 ak0 = *(const short8*)&Ks[krow][quad * 8];
        short8 ak1 = *(const short8*)&Ks[krow][32 + quad * 8];
        floatx4 s = (floatx4){0.f, 0.f, 0.f, 0.f};
        s = __builtin_amdgcn_mfma_f32_16x16x32_bf16(ak0, aq0, s, 0, 0, 0);
        s = __builtin_amdgcn_mfma_f32_16x16x32_bf16(ak1, aq1, s, 0, 0, 0);
        sfrag[kb] = s;
    }

    const float rowc = alibi_q - skb16 * (float)(kt * 4);
    float sv[4][4];
    float rm = -INFINITY;
#pragma unroll
    for (int kb = 0; kb < 4; kb++) {
        const float rck = rowc - skb16 * (float)kb;
#pragma unroll
        for (int r = 0; r < 4; r++) {
            float s = fmaf(sfrag[kb][r], qs2, rck - skq4[r]);
            if (domask) {
                const int k = kt * 64 + kb * 16 + quad * 4 + r;
                s = (k <= qrow) ? s : -INFINITY;
            }
            sv[kb][r] = s;
            rm = fmaxf(rm, s);
        }
    }
    rm = fmaxf(rm, __shfl_xor(rm, 16));
    rm = fmaxf(rm, __shfl_xor(rm, 32));

    if (__any(rm > m_row)) {
        const float mn = fmaxf(rm, m_row);
        const float corr = exp2f(m_row - mn);
        m_row = mn;
        l_row *= corr;
        float cr[4];
#pragma unroll
        for (int r = 0; r < 4; r++)
            cr[r] = __shfl(corr, (lane & 48) + quad * 4 + r);
#pragma unroll
        for (int db = 0; db < 4; db++)
#pragma unroll
            for (int r = 0; r < 4; r++) acc[db][r] *= cr[r];
    }

    float rs = 0.f;
#pragma unroll
    for (int kb = 0; kb < 4; kb++) {
        const float p0 = exp2f(sv[kb][0] - m_row);
        const float p1 = exp2f(sv[kb][1] - m_row);
        const float p2 = exp2f(sv[kb][2] - m_row);
        const float p3 = exp2f(sv[kb][3] - m_row);
        rs += (p0 + p1) + (p2 + p3);
        ushort4 pw;
        pw.x = f2b(p0); pw.y = f2b(p1); pw.z = f2b(p2); pw.w = f2b(p3);
        *(ushort4*)&Ps[w * 16 + l16][kb * 16 + quad * 4] = pw;
    }
    rs += __shfl_xor(rs, 16);
    rs += __shfl_xor(rs, 32);
    l_row += rs;

    short8 ap0 = *(const short8*)&Ps[w * 16 + l16][quad * 8];
    short8 ap1 = *(const short8*)&Ps[w * 16 + l16][32 + quad * 8];
#pragma unroll
    for (int db = 0; db < 4; db++) {
        const int dv = db * 16 + l16;
        const int svw = ((db * 4 + (l16 >> 2)) & 7) << 3;
        short8 bv0 = *(const short8*)&Vt[dv][(quad * 8) ^ svw];
        short8 bv1 = *(const short8*)&Vt[dv][(32 + quad * 8) ^ svw];
        acc[db] = __builtin_amdgcn_mfma_f32_16x16x32_bf16(ap0, bv0, acc[db], 0, 0, 0);
        acc[db] = __builtin_amdgcn_mfma_f32_16x16x32_bf16(ap1, bv1, acc[db], 0, 0, 0);
    }
}

__global__ __launch_bounds__(256) void attn_mfma_kernel(
        const ushort* __restrict__ qkv, ushort* __restrict__ y,
        float* __restrict__ opart, float* __restrict__ mpart,
        float* __restrict__ lpart, int B, int T) {
    const int C3 = 3 * N_EMBD;

    const int lin = xcd_swizzle(blockIdx.x, gridDim.x);
    const int bh = lin / 48;
    const int s  = lin % 48;
    int qt, cc, ktb_i, kte;
    bool split;
    if (s < 32) {
        split = true;
        qt = 31 - (s >> 1);
        cc = s & 1;
        const int hc = (qt + 2) >> 1;
        ktb_i = cc ? hc : 0;
        kte   = cc ? qt : hc - 1;
    } else {
        split = false;
        qt = 47 - s;
        cc = 0;
        ktb_i = 0;
        kte = qt;
    }
    const int b = bh >> 4, h = bh & 15;

    const int tid  = threadIdx.x;
    const int lane = tid & 63;
    const int w    = tid >> 6;
    const int quad = lane >> 4;
    const int l16  = lane & 15;

    __shared__ ushort QPs[64][AT_PAD];
    __shared__ ushort Ks[64][AT_PAD];
    __shared__ ushort Vt[64][AT_PAD];

    const float slope  = exp2f(-0.5f * (float)(h + 1));
    const float slope2 = slope * LOG2E;
    const float qs2    = 0.125f * LOG2E;

    const int q0 = qt * 64;
    const int qrow = q0 + w * 16 + l16;
    const float alibi_q = slope2 * (float)qrow;
    const float skb16   = slope2 * 16.f;
    float skq4[4];
#pragma unroll
    for (int r = 0; r < 4; r++) skq4[r] = slope2 * (float)(quad * 4 + r);

    const size_t hb = (size_t)b * T * C3 + (size_t)h * HEAD_D;

    int srow[4], sd0[4], svr[4];
#pragma unroll
    for (int i = 0; i < 4; i++) {
        const int idx = tid + i * 256;
        srow[i] = idx >> 4;
        sd0[i]  = (idx & 15) * 4;
        svr[i]  = srow[i] ^ ((idx & 7) << 3);
    }

#pragma unroll
    for (int i = 0; i < 4; i++) {
        *(ushort4*)&QPs[srow[i]][sd0[i]] =
            *(const ushort4*)&qkv[hb + (size_t)(q0 + srow[i]) * C3 + sd0[i]];
    }
    __syncthreads();

    const int mrow = w * 16 + l16;
    short8 aq0 = *(const short8*)&QPs[mrow][quad * 8];
    short8 aq1 = *(const short8*)&QPs[mrow][32 + quad * 8];

    float m_row = -INFINITY, l_row = 0.f;
    floatx4 acc[4];
#pragma unroll
    for (int r = 0; r < 4; r++) acc[r] = (floatx4){0.f, 0.f, 0.f, 0.f};

#pragma unroll
    for (int i = 0; i < 4; i++) {
        const size_t src = hb + (size_t)(ktb_i * 64 + srow[i]) * C3 + sd0[i];
        *(ushort4*)&Ks[srow[i]][sd0[i]] = *(const ushort4*)&qkv[src + N_EMBD];
        ushort4 vv = *(const ushort4*)&qkv[src + 2 * N_EMBD];
        Vt[sd0[i] + 0][svr[i]] = vv.x;
        Vt[sd0[i] + 1][svr[i]] = vv.y;
        Vt[sd0[i] + 2][svr[i]] = vv.z;
        Vt[sd0[i] + 3][svr[i]] = vv.w;
    }
    __syncthreads();

    for (int kt = ktb_i; kt <= kte; kt++) {
        ushort4 kreg[4], vreg[4];
        const bool pf = (kt < kte);
        if (pf) {
#pragma unroll
            for (int i = 0; i < 4; i++) {
                const size_t src =
                    hb + (size_t)((kt + 1) * 64 + srow[i]) * C3 + sd0[i];
                kreg[i] = *(const ushort4*)&qkv[src + N_EMBD];
                vreg[i] = *(const ushort4*)&qkv[src + 2 * N_EMBD];
            }
        }

        attn_tile_step(aq0, aq1, Ks, Vt, QPs, m_row, l_row, acc,
                       qrow, kt, kt == qt, qs2, alibi_q, skb16, skq4,
                       w, quad, l16, lane);
        __syncthreads();

        if (pf) {
#pragma unroll
            for (int i = 0; i < 4; i++) {
                *(ushort4*)&Ks[srow[i]][sd0[i]] = kreg[i];
                Vt[sd0[i] + 0][svr[i]] = vreg[i].x;
                Vt[sd0[i] + 1][svr[i]] = vreg[i].y;
                Vt[sd0[i] + 2][svr[i]] = vreg[i].z;
                Vt[sd0[i] + 3][svr[i]] = vreg[i].w;
            }
        }
        __syncthreads();
    }

    if (!split) {
        const float li = 1.f / l_row;
        float ia[4];
#pragma unroll
        for (int r = 0; r < 4; r++)
            ia[r] = __shfl(li, (lane & 48) + quad * 4 + r);
#pragma unroll
        for (int r = 0; r < 4; r++) {
            const int qa = q0 + w * 16 + quad * 4 + r;
#pragma unroll
            for (int db = 0; db < 4; db++) {
                y[((size_t)b * T + qa) * N_EMBD + h * HEAD_D + db * 16 + l16] =
                    f2b(acc[db][r] * ia[r]);
            }
        }
    } else {
        const int pidx = (bh * 16 + (qt - 16)) * 2 + cc;
#pragma unroll
        for (int r = 0; r < 4; r++) {
            const int row = w * 16 + quad * 4 + r;
#pragma unroll
            for (int db = 0; db < 4; db++) {
                opart[((size_t)pidx * 64 + row) * 64 + db * 16 + l16] =
                    acc[db][r];
            }
        }
        if (quad == 0) {
            mpart[pidx * 64 + w * 16 + l16] = m_row;
            lpart[pidx * 64 + w * 16 + l16] = l_row;
        }
    }
}

// ---------------------------------------------------------------------------
// Attention combine: merge the 2 KV-half partials for each split q-tile.
// ---------------------------------------------------------------------------
__global__ __launch_bounds__(256) void attn_combine_kernel(
        const float* __restrict__ opart, const float* __restrict__ mpart,
        const float* __restrict__ lpart, ushort* __restrict__ y, int T) {
    const int x  = blockIdx.x;
    const int bh = x >> 4;
    const int qt = 16 + (x & 15);
    const int b  = bh >> 4, h = bh & 15;
    const int t  = threadIdx.x;
    const int row = t >> 2;
    const int dq  = (t & 3) << 4;
    const int p0 = x * 2, p1 = p0 + 1;

    const float m0 = mpart[p0 * 64 + row], m1 = mpart[p1 * 64 + row];
    const float l0 = lpart[p0 * 64 + row], l1 = lpart[p1 * 64 + row];
    const float M  = fmaxf(m0, m1);
    const float w0 = exp2f(m0 - M), w1 = exp2f(m1 - M);
    const float inv = 1.f / (l0 * w0 + l1 * w1);

    const float* o0 = &opart[((size_t)p0 * 64 + row) * 64 + dq];
    const float* o1 = &opart[((size_t)p1 * 64 + row) * 64 + dq];
    ushort* yr = &y[((size_t)b * T + qt * 64 + row) * N_EMBD + h * HEAD_D + dq];
#pragma unroll
    for (int j = 0; j < 16; j += 4) {
        const float4 a = *(const float4*)&o0[j];
        const float4 c = *(const float4*)&o1[j];
        yr[j + 0] = f2b((a.x * w0 + c.x * w1) * inv);
        yr[j + 1] = f2b((a.y * w0 + c.y * w1) * inv);
        yr[j + 2] = f2b((a.z * w0 + c.z * w1) * inv);
        yr[j + 3] = f2b((a.w * w0 + c.w * w1) * inv);
    }
}

// ---------------------------------------------------------------------------
extern "C" void kernel_launch(void* const* d_in, const int* in_sizes, int n_in,
                              void* d_out, int out_size, void* d_ws, size_t ws_size,
                              hipStream_t stream) {
    const int B = 2, T = 2048, C = N_EMBD;
    const int M = B * T;

    const float* x      = (const float*)d_in[0];
    const float* ln1_w  = (const float*)d_in[1];
    const float* ln1_b  = (const float*)d_in[2];
    const float* w_qkv  = (const float*)d_in[3];
    const float* b_qkv  = (const float*)d_in[4];
    const float* w_proj = (const float*)d_in[5];
    const float* b_proj = (const float*)d_in[6];
    const float* ln2_w  = (const float*)d_in[7];
    const float* ln2_b  = (const float*)d_in[8];
    const float* w_fc   = (const float*)d_in[9];
    const float* b_fc   = (const float*)d_in[10];
    const float* w_fc2  = (const float*)d_in[11];
    const float* b_fc2  = (const float*)d_in[12];
    float* out = (float*)d_out;

    char* ws = (char*)d_ws;
    size_t off = 0;
    ushort* wt_qkv  = (ushort*)(ws + off); off += (size_t)3 * C * C * 2;
    ushort* wt_proj = (ushort*)(ws + off); off += (size_t)C * C * 2;
    ushort* wt_fc   = (ushort*)(ws + off); off += (size_t)4 * C * C * 2;
    ushort* wt_fc2  = (ushort*)(ws + off); off += (size_t)4 * C * C * 2;
    ushort* h16     = (ushort*)(ws + off); off += (size_t)M * C * 2;
    ushort* qkv16   = (ushort*)(ws + off); off += (size_t)M * 3 * C * 2;
    ushort* y16     = (ushort*)(ws + off); off += (size_t)M * C * 2;
    ushort* fc16    = (ushort*)(ws + off); off += (size_t)M * 4 * C * 2;

    // 0. weight transpose+convert
    convtrans_kernel<<<dim3(3 * C / 32, C / 32), 256, 0, stream>>>(w_qkv, wt_qkv, C, 3 * C);
    convtrans_kernel<<<dim3(C / 32, C / 32), 256, 0, stream>>>(w_proj, wt_proj, C, C);
    convtrans_kernel<<<dim3(4 * C / 32, C / 32), 256, 0, stream>>>(w_fc, wt_fc, C, 4 * C);
    convtrans_kernel<<<dim3(C / 32, 4 * C / 32), 256, 0, stream>>>(w_fc2, wt_fc2, 4 * C, C);

    // 1. h = LN1(x) -> bf16
    ln_kernel<<<M, 256, 0, stream>>>(x, ln1_w, ln1_b, h16);

    // 2. qkv = h @ w_qkv + b_qkv -> bf16
    gemm_bf16_kernel<<<dim3(3 * C / 128, M / 128), 256, 0, stream>>>(
        h16, wt_qkv, b_qkv, nullptr, nullptr, qkv16, M, 3 * C, C, 0);

    // 3. flash ALiBi attention, KV-split long tiles; partials in fc16 region.
    float* aop = (float*)fc16;
    float* amp = aop + (size_t)1024 * 64 * 64;
    float* alp = amp + (size_t)1024 * 64;
    attn_mfma_kernel<<<32 * 48, 256, 0, stream>>>(
        qkv16, y16, aop, amp, alp, B, T);
    attn_combine_kernel<<<512, 256, 0, stream>>>(aop, amp, alp, y16, T);

    // 4. proj split-K=2: partials into h16+qkv16 (both dead), then
    //    out = x + p0 + p1 + b_proj.
    float* pp = (float*)h16;   // 2 x 16 MB fits in h16(8)+qkv16(24)
    gemm_bf16_kernel<<<dim3(C / 128, M / 128, 2), 256, 0, stream>>>(
        y16, wt_proj, nullptr, nullptr, pp, nullptr, M, C, C, 0);
    combine_kernel<<<(M * C) / (256 * 4), 256, 0, stream>>>(
        pp, pp + (size_t)M * C, b_proj, x, out);

    // 5. h = LN2(x1) -> bf16
    ln_kernel<<<M, 256, 0, stream>>>(out, ln2_w, ln2_b, h16);

    // 6. fc = gelu(h @ w_fc + b_fc) -> bf16
    gemm_bf16_kernel<<<dim3(4 * C / 128, M / 128), 256, 0, stream>>>(
        h16, wt_fc, b_fc, nullptr, nullptr, fc16, M, 4 * C, C, 1);

    // 7. fc2 split-K=2, BK=64 kernel (grid-capped at 2/CU so 64KB LDS is
    //    free); partials in h16 region (dead after fc consumed h16), then
    //    out = out(x1) + p0 + p1 + b_fc2.
    float* part = (float*)h16;
    gemm_bf16_k64_kernel<<<dim3(C / 128, M / 128, 2), 256, 0, stream>>>(
        fc16, wt_fc2, part, M, C, 4 * C);
    combine_kernel<<<(M * C) / (256 * 4), 256, 0, stream>>>(
        part, part + (size_t)M * C, b_fc2, out, out);
}

// Round 12
// 393.218 us; speedup vs baseline: 1.1429x; 1.0080x over previous
//
#include <hip/hip_runtime.h>
#include <hip/hip_bf16.h>
#include <math.h>

#define N_EMBD 1024
#define N_HEADC 16
#define HEAD_D 64

typedef __attribute__((ext_vector_type(8))) short short8;
typedef __attribute__((ext_vector_type(4))) float floatx4;

__device__ __forceinline__ ushort f2b(float f) {
    __hip_bfloat16 h = __float2bfloat16(f);
    return *reinterpret_cast<ushort*>(&h);
}

__device__ __forceinline__ void async_cp16(const void* gsrc, void* ldst) {
    __builtin_amdgcn_global_load_lds(
        (const __attribute__((address_space(1))) void*)gsrc,
        (__attribute__((address_space(3))) void*)ldst, 16, 0, 0);
}

// Bijective XCD-chunk swizzle (m204 form).
__device__ __forceinline__ int xcd_swizzle(int bid, int nwg) {
    const int q = nwg >> 3, r = nwg & 7;
    const int xcd = bid & 7, loc = bid >> 3;
    return (xcd < r ? xcd * (q + 1) : r * (q + 1) + (xcd - r) * q) + loc;
}

// ---------------------------------------------------------------------------
// LayerNorm: fp32 in, bf16 out. One block (256 thr) per row of C=1024.
// ---------------------------------------------------------------------------
__global__ __launch_bounds__(256) void ln_kernel(const float* __restrict__ x,
                                                 const float* __restrict__ w,
                                                 const float* __restrict__ b,
                                                 ushort* __restrict__ out) {
    const int row = blockIdx.x;
    const int t = threadIdx.x;
    const float4 v = reinterpret_cast<const float4*>(x + (size_t)row * N_EMBD)[t];
    float s  = v.x + v.y + v.z + v.w;
    float ss = v.x * v.x + v.y * v.y + v.z * v.z + v.w * v.w;
    for (int o = 32; o > 0; o >>= 1) {
        s  += __shfl_down(s, o);
        ss += __shfl_down(ss, o);
    }
    __shared__ float as_[4], ass_[4];
    const int wid = t >> 6, lane = t & 63;
    if (lane == 0) { as_[wid] = s; ass_[wid] = ss; }
    __syncthreads();
    const float ts  = as_[0] + as_[1] + as_[2] + as_[3];
    const float tss = ass_[0] + ass_[1] + ass_[2] + ass_[3];
    const float mu  = ts * (1.f / N_EMBD);
    const float var = tss * (1.f / N_EMBD) - mu * mu;
    const float inv = rsqrtf(var + 1e-5f);
    const float4 wv = reinterpret_cast<const float4*>(w)[t];
    const float4 bv = reinterpret_cast<const float4*>(b)[t];
    ushort4 o;
    o.x = f2b((v.x - mu) * inv * wv.x + bv.x);
    o.y = f2b((v.y - mu) * inv * wv.y + bv.y);
    o.z = f2b((v.z - mu) * inv * wv.z + bv.z);
    o.w = f2b((v.w - mu) * inv * wv.w + bv.w);
    reinterpret_cast<ushort4*>(out + (size_t)row * N_EMBD)[t] = o;
}

// ---------------------------------------------------------------------------
// Fused split-K combine + LayerNorm. One block per row:
//   v = res + p0 + p1 + bias  -> out32 (x1), then LN(v) -> out16.
// Bit-identical to combine_kernel followed by ln_kernel.
// ---------------------------------------------------------------------------
__global__ __launch_bounds__(256) void combine_ln_kernel(
        const float* __restrict__ p0, const float* __restrict__ p1,
        const float* __restrict__ bias, const float* __restrict__ res,
        float* __restrict__ out32,
        const float* __restrict__ ln_w, const float* __restrict__ ln_b,
        ushort* __restrict__ out16) {
    const int row = blockIdx.x;
    const int t = threadIdx.x;
    const size_t i = (size_t)row * 256 + t;       // float4 index
    const float4 a  = ((const float4*)p0)[i];
    const float4 c  = ((const float4*)p1)[i];
    const float4 bb = ((const float4*)bias)[t];
    const float4 rr = ((const float4*)res)[i];
    float4 v;
    v.x = rr.x + a.x + c.x + bb.x;
    v.y = rr.y + a.y + c.y + bb.y;
    v.z = rr.z + a.z + c.z + bb.z;
    v.w = rr.w + a.w + c.w + bb.w;
    ((float4*)out32)[i] = v;

    float s  = v.x + v.y + v.z + v.w;
    float ss = v.x * v.x + v.y * v.y + v.z * v.z + v.w * v.w;
    for (int o = 32; o > 0; o >>= 1) {
        s  += __shfl_down(s, o);
        ss += __shfl_down(ss, o);
    }
    __shared__ float as_[4], ass_[4];
    const int wid = t >> 6, lane = t & 63;
    if (lane == 0) { as_[wid] = s; ass_[wid] = ss; }
    __syncthreads();
    const float ts  = as_[0] + as_[1] + as_[2] + as_[3];
    const float tss = ass_[0] + ass_[1] + ass_[2] + ass_[3];
    const float mu  = ts * (1.f / N_EMBD);
    const float var = tss * (1.f / N_EMBD) - mu * mu;
    const float inv = rsqrtf(var + 1e-5f);
    const float4 wv = ((const float4*)ln_w)[t];
    const float4 bv = ((const float4*)ln_b)[t];
    ushort4 o;
    o.x = f2b((v.x - mu) * inv * wv.x + bv.x);
    o.y = f2b((v.y - mu) * inv * wv.y + bv.y);
    o.z = f2b((v.z - mu) * inv * wv.z + bv.z);
    o.w = f2b((v.w - mu) * inv * wv.w + bv.w);
    ((ushort4*)(out16 + (size_t)row * N_EMBD))[t] = o;
}

// ---------------------------------------------------------------------------
// Transpose + convert: W[K,N] fp32 -> Wt[N,K] bf16. 32x32 tiles, 256 thr.
// ---------------------------------------------------------------------------
__global__ void convtrans_kernel(const float* __restrict__ W,
                                 ushort* __restrict__ Wt, int K, int N) {
    __shared__ float tile[32][33];
    const int tid = threadIdx.x;
    const int r = tid >> 3;
    const int c4 = (tid & 7) * 4;
    const int bx = blockIdx.x, by = blockIdx.y;

    float4 v = *(const float4*)&W[((size_t)(by * 32 + r)) * N + bx * 32 + c4];
    tile[r][c4 + 0] = v.x; tile[r][c4 + 1] = v.y;
    tile[r][c4 + 2] = v.z; tile[r][c4 + 3] = v.w;
    __syncthreads();

    ushort4 u;
    u.x = f2b(tile[c4 + 0][r]); u.y = f2b(tile[c4 + 1][r]);
    u.z = f2b(tile[c4 + 2][r]); u.w = f2b(tile[c4 + 3][r]);
    *(ushort4*)&Wt[((size_t)(bx * 32 + r)) * K + by * 32 + c4] = u;
}

// ---------------------------------------------------------------------------
// 128^2 bf16 MFMA GEMM: counted-vmcnt double buffer (R7 verified structure).
// Optional split-K via gridDim.z: partial z written at out32 + z*M*N.
// ---------------------------------------------------------------------------
__device__ __forceinline__ void gemm_stage(
        const ushort* __restrict__ A, const ushort* __restrict__ Bt,
        ushort* As, ushort* Bs,
        int m0, int n0, int K, int k0, int w, int lane) {
#pragma unroll
    for (int l = 0; l < 2; l++) {
        const int cbase = w * 128 + l * 64;
        const int c = cbase + lane;
        const int row = c >> 2, kc8 = (c & 3) * 8;
        async_cp16(A  + (size_t)(m0 + row) * K + k0 + kc8, &As[cbase * 8]);
        async_cp16(Bt + (size_t)(n0 + row) * K + k0 + kc8, &Bs[cbase * 8]);
    }
}
// one gemm_stage = 4 global_load_lds per wave -> vmcnt quantum is 4.

__device__ __forceinline__ void gemm_compute(
        const ushort* As, const ushort* Bs, floatx4 (*acc)[4],
        int wm, int wn, int quad, int l16) {
    short8 a[4], bf[4];
#pragma unroll
    for (int i = 0; i < 4; i++)
        a[i] = *(const short8*)&As[(wm * 64 + i * 16 + l16) * 32 + quad * 8];
#pragma unroll
    for (int j = 0; j < 4; j++)
        bf[j] = *(const short8*)&Bs[(wn * 64 + j * 16 + l16) * 32 + quad * 8];
#pragma unroll
    for (int i = 0; i < 4; i++)
#pragma unroll
        for (int j = 0; j < 4; j++)
            acc[i][j] = __builtin_amdgcn_mfma_f32_16x16x32_bf16(
                a[i], bf[j], acc[i][j], 0, 0, 0);
}

__device__ __forceinline__ void gemm_epilogue(
        floatx4 (*acc)[4], const float* bias, const float* residual,
        float* out32, ushort* out16, int M, int N,
        int m0, int n0, int wm, int wn, int quad, int l16, int do_gelu) {
#pragma unroll
    for (int i = 0; i < 4; i++) {
#pragma unroll
        for (int j = 0; j < 4; j++) {
            const int nn = n0 + wn * 64 + j * 16 + l16;
            const float bv = bias ? bias[nn] : 0.f;
#pragma unroll
            for (int r = 0; r < 4; r++) {
                const int mm = m0 + wm * 64 + i * 16 + quad * 4 + r;
                float v = acc[i][j][r] + bv;
                if (do_gelu) v = 0.5f * v * (1.f + erff(v * 0.70710678118654752f));
                if (residual) v += residual[(size_t)mm * N + nn];
                if (out32) out32[(size_t)mm * N + nn] = v;
                if (out16) out16[(size_t)mm * N + nn] = f2b(v);
            }
        }
    }
}

__global__ __launch_bounds__(256) void gemm_bf16_kernel(
        const ushort* __restrict__ A,
        const ushort* __restrict__ Bt,
        const float* __restrict__ bias,
        const float* __restrict__ residual,
        float* __restrict__ out32,
        ushort* __restrict__ out16,
        int M, int N, int K, int do_gelu) {
    __shared__ ushort As[2][128 * 32];
    __shared__ ushort Bs[2][128 * 32];

    const int tid  = threadIdx.x;
    const int w    = tid >> 6;
    const int lane = tid & 63;
    const int quad = lane >> 4;
    const int l16  = lane & 15;
    const int wm   = w >> 1;
    const int wn   = w & 1;

    int bid = blockIdx.y * gridDim.x + blockIdx.x;
    bid = xcd_swizzle(bid, gridDim.x * gridDim.y);
    const int bx = bid % gridDim.x;
    const int by = bid / gridDim.x;
    const int m0 = by * 128;
    const int n0 = bx * 128;

    const int kchunk = K / gridDim.z;
    const int kbeg   = blockIdx.z * kchunk;
    if (gridDim.z > 1)
        out32 += (size_t)blockIdx.z * M * N;

    floatx4 acc[4][4];
#pragma unroll
    for (int i = 0; i < 4; i++)
#pragma unroll
        for (int j = 0; j < 4; j++) acc[i][j] = (floatx4){0.f, 0.f, 0.f, 0.f};

    const int nt = kchunk >> 5;

    gemm_stage(A, Bt, As[0], Bs[0], m0, n0, K, kbeg, w, lane);
    gemm_stage(A, Bt, As[1], Bs[1], m0, n0, K, kbeg + 32, w, lane);

    for (int t = 0; t < nt; t++) {
        if (t + 1 < nt) {
            asm volatile("s_waitcnt vmcnt(4)" ::: "memory");
        } else {
            asm volatile("s_waitcnt vmcnt(0)" ::: "memory");
        }
        __builtin_amdgcn_sched_barrier(0);
        __builtin_amdgcn_s_barrier();

        gemm_compute(As[t & 1], Bs[t & 1], acc, wm, wn, quad, l16);

        __builtin_amdgcn_s_barrier();
        if (t + 2 < nt)
            gemm_stage(A, Bt, As[t & 1], Bs[t & 1],
                       m0, n0, K, kbeg + ((t + 2) << 5), w, lane);
    }

    gemm_epilogue(acc, bias, residual, out32, out16, M, N,
                  m0, n0, wm, wn, quad, l16, do_gelu);
}

// ---------------------------------------------------------------------------
// BK=64 variant: two 32-K sub-tiles per step (half the barriers/waits).
// 64 KB LDS dbuf -> 2 blocks/CU; used where residency is already <=2/CU
// (fc: grid 1024 but ~2 resident; fc2 split-K=2: 512 blocks).
// vmcnt quantum is 8 (2 sub-stages x 4 loads). Full epilogue support.
// ---------------------------------------------------------------------------
__global__ __launch_bounds__(256) void gemm_bf16_k64_kernel(
        const ushort* __restrict__ A,
        const ushort* __restrict__ Bt,
        const float* __restrict__ bias,
        const float* __restrict__ residual,
        float* __restrict__ out32,
        ushort* __restrict__ out16,
        int M, int N, int K, int do_gelu) {
    __shared__ ushort As[2][2 * 128 * 32];
    __shared__ ushort Bs[2][2 * 128 * 32];

    const int tid  = threadIdx.x;
    const int w    = tid >> 6;
    const int lane = tid & 63;
    const int quad = lane >> 4;
    const int l16  = lane & 15;
    const int wm   = w >> 1;
    const int wn   = w & 1;

    int bid = blockIdx.y * gridDim.x + blockIdx.x;
    bid = xcd_swizzle(bid, gridDim.x * gridDim.y);
    const int bx = bid % gridDim.x;
    const int by = bid / gridDim.x;
    const int m0 = by * 128;
    const int n0 = bx * 128;

    const int kchunk = K / gridDim.z;
    const int kbeg   = blockIdx.z * kchunk;
    if (gridDim.z > 1)
        out32 += (size_t)blockIdx.z * M * N;

    floatx4 acc[4][4];
#pragma unroll
    for (int i = 0; i < 4; i++)
#pragma unroll
        for (int j = 0; j < 4; j++) acc[i][j] = (floatx4){0.f, 0.f, 0.f, 0.f};

    const int nt = kchunk >> 6;   // K-steps of 64

    gemm_stage(A, Bt, As[0],        Bs[0],        m0, n0, K, kbeg,      w, lane);
    gemm_stage(A, Bt, As[0] + 4096, Bs[0] + 4096, m0, n0, K, kbeg + 32, w, lane);
    gemm_stage(A, Bt, As[1],        Bs[1],        m0, n0, K, kbeg + 64, w, lane);
    gemm_stage(A, Bt, As[1] + 4096, Bs[1] + 4096, m0, n0, K, kbeg + 96, w, lane);

    for (int t = 0; t < nt; t++) {
        if (t + 1 < nt) {
            asm volatile("s_waitcnt vmcnt(8)" ::: "memory");
        } else {
            asm volatile("s_waitcnt vmcnt(0)" ::: "memory");
        }
        __builtin_amdgcn_sched_barrier(0);
        __builtin_amdgcn_s_barrier();

        gemm_compute(As[t & 1],        Bs[t & 1],        acc, wm, wn, quad, l16);
        gemm_compute(As[t & 1] + 4096, Bs[t & 1] + 4096, acc, wm, wn, quad, l16);

        __builtin_amdgcn_s_barrier();
        if (t + 2 < nt) {
            const int k2 = kbeg + ((t + 2) << 6);
            gemm_stage(A, Bt, As[t & 1],        Bs[t & 1],        m0, n0, K, k2,      w, lane);
            gemm_stage(A, Bt, As[t & 1] + 4096, Bs[t & 1] + 4096, m0, n0, K, k2 + 32, w, lane);
        }
    }

    gemm_epilogue(acc, bias, residual, out32, out16, M, N,
                  m0, n0, wm, wn, quad, l16, do_gelu);
}

// ---------------------------------------------------------------------------
// Split-K combine: out = res + p0 + p1 + bias. One float4 per thread.
// (res may alias out: each thread reads/writes only its own element.)
// ---------------------------------------------------------------------------
__global__ __launch_bounds__(256) void combine_kernel(
        const float* __restrict__ p0, const float* __restrict__ p1,
        const float* __restrict__ bias, const float* __restrict__ res,
        float* __restrict__ out) {
    const int i = blockIdx.x * 256 + threadIdx.x;
    const float4 a = ((const float4*)p0)[i];
    const float4 c = ((const float4*)p1)[i];
    const float4 bb = ((const float4*)bias)[i & 255];
    const float4 rr = ((const float4*)res)[i];
    float4 o;
    o.x = rr.x + a.x + c.x + bb.x;
    o.y = rr.y + a.y + c.y + bb.y;
    o.z = rr.z + a.z + c.z + bb.z;
    o.w = rr.w + a.w + c.w + bb.w;
    ((float4*)out)[i] = o;
}

// ---------------------------------------------------------------------------
// Flash ALiBi attention, SWAPPED QK^T (unchanged from R6/R7).
// ---------------------------------------------------------------------------
#define AT_PAD 72
#define LOG2E 1.4426950408889634f

__device__ __forceinline__ void attn_tile_step(
        short8 aq0, short8 aq1,
        ushort (*__restrict__ Ks)[AT_PAD],
        ushort (*__restrict__ Vt)[AT_PAD],
        ushort (*__restrict__ Ps)[AT_PAD],
        float& m_row, float& l_row, floatx4* acc,
        int qrow, int kt, bool domask,
        float qs2, float alibi_q, float skb16, const float* skq4,
        int w, int quad, int l16, int lane) {
    floatx4 sfrag[4];
#pragma unroll
    for (int kb = 0; kb < 4; kb++) {
        const int krow = kb * 16 + l16;
        short8 ak0 = *(const short8*)&Ks[krow][quad * 8];
        short8 ak1 = *(const short8*)&Ks[krow][32 + quad * 8];
        floatx4 s = (floatx4){0.f, 0.f, 0.f, 0.f};
        s = __builtin_amdgcn_mfma_f32_16x16x32_bf16(ak0, aq0, s, 0, 0, 0);
        s = __builtin_amdgcn_mfma_f32_16x16x32_bf16(ak1, aq1, s, 0, 0, 0);
        sfrag[kb] = s;
    }

    const float rowc = alibi_q - skb16 * (float)(kt * 4);
    float sv[4][4];
    float rm = -INFINITY;
#pragma unroll
    for (int kb = 0; kb < 4; kb++) {
        const float rck = rowc - skb16 * (float)kb;
#pragma unroll
        for (int r = 0; r < 4; r++) {
            float s = fmaf(sfrag[kb][r], qs2, rck - skq4[r]);
            if (domask) {
                const int k = kt * 64 + kb * 16 + quad * 4 + r;
                s = (k <= qrow) ? s : -INFINITY;
            }
            sv[kb][r] = s;
            rm = fmaxf(rm, s);
        }
    }
    rm = fmaxf(rm, __shfl_xor(rm, 16));
    rm = fmaxf(rm, __shfl_xor(rm, 32));

    if (__any(rm > m_row)) {
        const float mn = fmaxf(rm, m_row);
        const float corr = exp2f(m_row - mn);
        m_row = mn;
        l_row *= corr;
        float cr[4];
#pragma unroll
        for (int r = 0; r < 4; r++)
            cr[r] = __shfl(corr, (lane & 48) + quad * 4 + r);
#pragma unroll
        for (int db = 0; db < 4; db++)
#pragma unroll
            for (int r = 0; r < 4; r++) acc[db][r] *= cr[r];
    }

    float rs = 0.f;
#pragma unroll
    for (int kb = 0; kb < 4; kb++) {
        const float p0 = exp2f(sv[kb][0] - m_row);
        const float p1 = exp2f(sv[kb][1] - m_row);
        const float p2 = exp2f(sv[kb][2] - m_row);
        const float p3 = exp2f(sv[kb][3] - m_row);
        rs += (p0 + p1) + (p2 + p3);
        ushort4 pw;
        pw.x = f2b(p0); pw.y = f2b(p1); pw.z = f2b(p2); pw.w = f2b(p3);
        *(ushort4*)&Ps[w * 16 + l16][kb * 16 + quad * 4] = pw;
    }
    rs += __shfl_xor(rs, 16);
    rs += __shfl_xor(rs, 32);
    l_row += rs;

    short8 ap0 = *(const short8*)&Ps[w * 16 + l16][quad * 8];
    short8 ap1 = *(const short8*)&Ps[w * 16 + l16][32 + quad * 8];
#pragma unroll
    for (int db = 0; db < 4; db++) {
        const int dv = db * 16 + l16;
        const int svw = ((db * 4 + (l16 >> 2)) & 7) << 3;
        short8 bv0 = *(const short8*)&Vt[dv][(quad * 8) ^ svw];
        short8 bv1 = *(const short8*)&Vt[dv][(32 + quad * 8) ^ svw];
        acc[db] = __builtin_amdgcn_mfma_f32_16x16x32_bf16(ap0, bv0, acc[db], 0, 0, 0);
        acc[db] = __builtin_amdgcn_mfma_f32_16x16x32_bf16(ap1, bv1, acc[db], 0, 0, 0);
    }
}

__global__ __launch_bounds__(256) void attn_mfma_kernel(
        const ushort* __restrict__ qkv, ushort* __restrict__ y,
        float* __restrict__ opart, float* __restrict__ mpart,
        float* __restrict__ lpart, int B, int T) {
    const int C3 = 3 * N_EMBD;

    const int lin = xcd_swizzle(blockIdx.x, gridDim.x);
    const int bh = lin / 48;
    const int s  = lin % 48;
    int qt, cc, ktb_i, kte;
    bool split;
    if (s < 32) {
        split = true;
        qt = 31 - (s >> 1);
        cc = s & 1;
        const int hc = (qt + 2) >> 1;
        ktb_i = cc ? hc : 0;
        kte   = cc ? qt : hc - 1;
    } else {
        split = false;
        qt = 47 - s;
        cc = 0;
        ktb_i = 0;
        kte = qt;
    }
    const int b = bh >> 4, h = bh & 15;

    const int tid  = threadIdx.x;
    const int lane = tid & 63;
    const int w    = tid >> 6;
    const int quad = lane >> 4;
    const int l16  = lane & 15;

    __shared__ ushort QPs[64][AT_PAD];
    __shared__ ushort Ks[64][AT_PAD];
    __shared__ ushort Vt[64][AT_PAD];

    const float slope  = exp2f(-0.5f * (float)(h + 1));
    const float slope2 = slope * LOG2E;
    const float qs2    = 0.125f * LOG2E;

    const int q0 = qt * 64;
    const int qrow = q0 + w * 16 + l16;
    const float alibi_q = slope2 * (float)qrow;
    const float skb16   = slope2 * 16.f;
    float skq4[4];
#pragma unroll
    for (int r = 0; r < 4; r++) skq4[r] = slope2 * (float)(quad * 4 + r);

    const size_t hb = (size_t)b * T * C3 + (size_t)h * HEAD_D;

    int srow[4], sd0[4], svr[4];
#pragma unroll
    for (int i = 0; i < 4; i++) {
        const int idx = tid + i * 256;
        srow[i] = idx >> 4;
        sd0[i]  = (idx & 15) * 4;
        svr[i]  = srow[i] ^ ((idx & 7) << 3);
    }

#pragma unroll
    for (int i = 0; i < 4; i++) {
        *(ushort4*)&QPs[srow[i]][sd0[i]] =
            *(const ushort4*)&qkv[hb + (size_t)(q0 + srow[i]) * C3 + sd0[i]];
    }
    __syncthreads();

    const int mrow = w * 16 + l16;
    short8 aq0 = *(const short8*)&QPs[mrow][quad * 8];
    short8 aq1 = *(const short8*)&QPs[mrow][32 + quad * 8];

    float m_row = -INFINITY, l_row = 0.f;
    floatx4 acc[4];
#pragma unroll
    for (int r = 0; r < 4; r++) acc[r] = (floatx4){0.f, 0.f, 0.f, 0.f};

#pragma unroll
    for (int i = 0; i < 4; i++) {
        const size_t src = hb + (size_t)(ktb_i * 64 + srow[i]) * C3 + sd0[i];
        *(ushort4*)&Ks[srow[i]][sd0[i]] = *(const ushort4*)&qkv[src + N_EMBD];
        ushort4 vv = *(const ushort4*)&qkv[src + 2 * N_EMBD];
        Vt[sd0[i] + 0][svr[i]] = vv.x;
        Vt[sd0[i] + 1][svr[i]] = vv.y;
        Vt[sd0[i] + 2][svr[i]] = vv.z;
        Vt[sd0[i] + 3][svr[i]] = vv.w;
    }
    __syncthreads();

    for (int kt = ktb_i; kt <= kte; kt++) {
        ushort4 kreg[4], vreg[4];
        const bool pf = (kt < kte);
        if (pf) {
#pragma unroll
            for (int i = 0; i < 4; i++) {
                const size_t src =
                    hb + (size_t)((kt + 1) * 64 + srow[i]) * C3 + sd0[i];
                kreg[i] = *(const ushort4*)&qkv[src + N_EMBD];
                vreg[i] = *(const ushort4*)&qkv[src + 2 * N_EMBD];
            }
        }

        attn_tile_step(aq0, aq1, Ks, Vt, QPs, m_row, l_row, acc,
                       qrow, kt, kt == qt, qs2, alibi_q, skb16, skq4,
                       w, quad, l16, lane);
        __syncthreads();

        if (pf) {
#pragma unroll
            for (int i = 0; i < 4; i++) {
                *(ushort4*)&Ks[srow[i]][sd0[i]] = kreg[i];
                Vt[sd0[i] + 0][svr[i]] = vreg[i].x;
                Vt[sd0[i] + 1][svr[i]] = vreg[i].y;
                Vt[sd0[i] + 2][svr[i]] = vreg[i].z;
                Vt[sd0[i] + 3][svr[i]] = vreg[i].w;
            }
        }
        __syncthreads();
    }

    if (!split) {
        const float li = 1.f / l_row;
        float ia[4];
#pragma unroll
        for (int r = 0; r < 4; r++)
            ia[r] = __shfl(li, (lane & 48) + quad * 4 + r);
#pragma unroll
        for (int r = 0; r < 4; r++) {
            const int qa = q0 + w * 16 + quad * 4 + r;
#pragma unroll
            for (int db = 0; db < 4; db++) {
                y[((size_t)b * T + qa) * N_EMBD + h * HEAD_D + db * 16 + l16] =
                    f2b(acc[db][r] * ia[r]);
            }
        }
    } else {
        const int pidx = (bh * 16 + (qt - 16)) * 2 + cc;
#pragma unroll
        for (int r = 0; r < 4; r++) {
            const int row = w * 16 + quad * 4 + r;
#pragma unroll
            for (int db = 0; db < 4; db++) {
                opart[((size_t)pidx * 64 + row) * 64 + db * 16 + l16] =
                    acc[db][r];
            }
        }
        if (quad == 0) {
            mpart[pidx * 64 + w * 16 + l16] = m_row;
            lpart[pidx * 64 + w * 16 + l16] = l_row;
        }
    }
}

// ---------------------------------------------------------------------------
// Attention combine: merge the 2 KV-half partials for each split q-tile.
// ---------------------------------------------------------------------------
__global__ __launch_bounds__(256) void attn_combine_kernel(
        const float* __restrict__ opart, const float* __restrict__ mpart,
        const float* __restrict__ lpart, ushort* __restrict__ y, int T) {
    const int x  = blockIdx.x;
    const int bh = x >> 4;
    const int qt = 16 + (x & 15);
    const int b  = bh >> 4, h = bh & 15;
    const int t  = threadIdx.x;
    const int row = t >> 2;
    const int dq  = (t & 3) << 4;
    const int p0 = x * 2, p1 = p0 + 1;

    const float m0 = mpart[p0 * 64 + row], m1 = mpart[p1 * 64 + row];
    const float l0 = lpart[p0 * 64 + row], l1 = lpart[p1 * 64 + row];
    const float M  = fmaxf(m0, m1);
    const float w0 = exp2f(m0 - M), w1 = exp2f(m1 - M);
    const float inv = 1.f / (l0 * w0 + l1 * w1);

    const float* o0 = &opart[((size_t)p0 * 64 + row) * 64 + dq];
    const float* o1 = &opart[((size_t)p1 * 64 + row) * 64 + dq];
    ushort* yr = &y[((size_t)b * T + qt * 64 + row) * N_EMBD + h * HEAD_D + dq];
#pragma unroll
    for (int j = 0; j < 16; j += 4) {
        const float4 a = *(const float4*)&o0[j];
        const float4 c = *(const float4*)&o1[j];
        yr[j + 0] = f2b((a.x * w0 + c.x * w1) * inv);
        yr[j + 1] = f2b((a.y * w0 + c.y * w1) * inv);
        yr[j + 2] = f2b((a.z * w0 + c.z * w1) * inv);
        yr[j + 3] = f2b((a.w * w0 + c.w * w1) * inv);
    }
}

// ---------------------------------------------------------------------------
extern "C" void kernel_launch(void* const* d_in, const int* in_sizes, int n_in,
                              void* d_out, int out_size, void* d_ws, size_t ws_size,
                              hipStream_t stream) {
    const int B = 2, T = 2048, C = N_EMBD;
    const int M = B * T;

    const float* x      = (const float*)d_in[0];
    const float* ln1_w  = (const float*)d_in[1];
    const float* ln1_b  = (const float*)d_in[2];
    const float* w_qkv  = (const float*)d_in[3];
    const float* b_qkv  = (const float*)d_in[4];
    const float* w_proj = (const float*)d_in[5];
    const float* b_proj = (const float*)d_in[6];
    const float* ln2_w  = (const float*)d_in[7];
    const float* ln2_b  = (const float*)d_in[8];
    const float* w_fc   = (const float*)d_in[9];
    const float* b_fc   = (const float*)d_in[10];
    const float* w_fc2  = (const float*)d_in[11];
    const float* b_fc2  = (const float*)d_in[12];
    float* out = (float*)d_out;

    char* ws = (char*)d_ws;
    size_t off = 0;
    ushort* wt_qkv  = (ushort*)(ws + off); off += (size_t)3 * C * C * 2;
    ushort* wt_proj = (ushort*)(ws + off); off += (size_t)C * C * 2;
    ushort* wt_fc   = (ushort*)(ws + off); off += (size_t)4 * C * C * 2;
    ushort* wt_fc2  = (ushort*)(ws + off); off += (size_t)4 * C * C * 2;
    ushort* h16     = (ushort*)(ws + off); off += (size_t)M * C * 2;
    ushort* qkv16   = (ushort*)(ws + off); off += (size_t)M * 3 * C * 2;
    ushort* y16     = (ushort*)(ws + off); off += (size_t)M * C * 2;
    ushort* fc16    = (ushort*)(ws + off); off += (size_t)M * 4 * C * 2;

    // 0. weight transpose+convert
    convtrans_kernel<<<dim3(3 * C / 32, C / 32), 256, 0, stream>>>(w_qkv, wt_qkv, C, 3 * C);
    convtrans_kernel<<<dim3(C / 32, C / 32), 256, 0, stream>>>(w_proj, wt_proj, C, C);
    convtrans_kernel<<<dim3(4 * C / 32, C / 32), 256, 0, stream>>>(w_fc, wt_fc, C, 4 * C);
    convtrans_kernel<<<dim3(C / 32, 4 * C / 32), 256, 0, stream>>>(w_fc2, wt_fc2, 4 * C, C);

    // 1. h = LN1(x) -> bf16
    ln_kernel<<<M, 256, 0, stream>>>(x, ln1_w, ln1_b, h16);

    // 2. qkv = h @ w_qkv + b_qkv -> bf16
    gemm_bf16_kernel<<<dim3(3 * C / 128, M / 128), 256, 0, stream>>>(
        h16, wt_qkv, b_qkv, nullptr, nullptr, qkv16, M, 3 * C, C, 0);

    // 3. flash ALiBi attention, KV-split long tiles; partials in fc16 region.
    float* aop = (float*)fc16;
    float* amp = aop + (size_t)1024 * 64 * 64;
    float* alp = amp + (size_t)1024 * 64;
    attn_mfma_kernel<<<32 * 48, 256, 0, stream>>>(
        qkv16, y16, aop, amp, alp, B, T);
    attn_combine_kernel<<<512, 256, 0, stream>>>(aop, amp, alp, y16, T);

    // 4+5. proj split-K=2 -> partials; fused combine+LN2:
    //      out = x + p0 + p1 + b_proj, h16 = LN2(out).
    float* pp = (float*)h16;   // 2 x 16 MB in h16(8)+qkv16(24), both dead
    gemm_bf16_kernel<<<dim3(C / 128, M / 128, 2), 256, 0, stream>>>(
        y16, wt_proj, nullptr, nullptr, pp, nullptr, M, C, C, 0);
    // NOTE: combine_ln writes h16 region? No: pp lives in h16+qkv16; LN
    // output goes to y16 region instead (y16 is dead after proj).
    ushort* h2 = y16;
    combine_ln_kernel<<<M, 256, 0, stream>>>(
        pp, pp + (size_t)M * C, b_proj, x, out, ln2_w, ln2_b, h2);

    // 6. fc = gelu(h2 @ w_fc + b_fc) -> bf16  (BK=64 kernel)
    gemm_bf16_k64_kernel<<<dim3(4 * C / 128, M / 128), 256, 0, stream>>>(
        h2, wt_fc, b_fc, nullptr, nullptr, fc16, M, 4 * C, C, 1);

    // 7. fc2 split-K=2, BK=64; partials in h16 region, then
    //    out = out(x1) + p0 + p1 + b_fc2.
    float* part = (float*)h16;
    gemm_bf16_k64_kernel<<<dim3(C / 128, M / 128, 2), 256, 0, stream>>>(
        fc16, wt_fc2, nullptr, nullptr, part, nullptr, M, C, 4 * C, 0);
    combine_kernel<<<(M * C) / (256 * 4), 256, 0, stream>>>(
        part, part + (size_t)M * C, b_fc2, out, out);
}